// Round 13
// baseline (224.922 us; speedup 1.0000x reference)
//
#include <hip/hip_runtime.h>
#include <hip/hip_bf16.h>
#include <math.h>

// Problem constants
#define BB 4
#define LL 512
#define DMODEL 1024
#define DSTATE 16
#define DCONV 4
#define DINNER 2048
#define DTRANK 64
#define MROWS (BB*LL)          // 2048 rows of (b,l)
#define G2KS 4                 // split-K factor for the N=96 GEMM
#define SCHUNK 32              // scan chunk length
#define SNC (LL / SCHUNK)      // 16 chunks

typedef __hip_bfloat16 bf16;
typedef __attribute__((ext_vector_type(8))) short short8;
typedef __attribute__((ext_vector_type(4))) short short4v;
typedef __attribute__((ext_vector_type(4))) float f32x4;

__device__ __forceinline__ float softplusf(float x) {
    return x > 20.f ? x : log1pf(__expf(x));
}

// Async global->LDS, 16B per lane. LDS dest is wave-uniform base + lane*16
// (linear); global src is per-lane. __syncthreads() drains vmcnt.
__device__ __forceinline__ void stage16(const void* g, void* l) {
    __builtin_amdgcn_global_load_lds(
        (const __attribute__((address_space(1))) void*)g,
        (__attribute__((address_space(3))) void*)l, 16, 0, 0);
}

// A has the Vim structure Aa[n] == (n+1)*Aa[0]?
__device__ __forceinline__ bool a_is_arange(const float* Aa) {
    bool ok = true;
#pragma unroll
    for (int n = 1; n < DSTATE; ++n) {
        float k = (float)(n + 1);
        ok = ok && (fabsf(Aa[n] - k * Aa[0]) <= 1e-4f * k * fabsf(Aa[0]));
    }
    return ok;
}

// ---------------------------------------------------------------------------
// bf16 MFMA TN GEMM: C[M][N](f32) = A[M][K](bf16) * W[N][K](bf16)^T
// 128x128 tile, 4 waves, linear [128][32] LDS staged via global_load_lds.
// EPI 0: none; 2: nan_to_num.
// ---------------------------------------------------------------------------
template<int EPI>
__global__ __launch_bounds__(256) void gemm_bf16(
    const bf16* __restrict__ A, const bf16* __restrict__ W,
    float* __restrict__ C, int N, int K, int lda, int ldw, int ldc)
{
    __shared__ bf16 lA[128 * 32];
    __shared__ bf16 lW[128 * 32];

    const int tid = threadIdx.x;
    const int lane = tid & 63;
    const int wid = tid >> 6;
    const int wr = wid >> 1;
    const int wc = wid & 1;
    const int rowBase = blockIdx.y * 128;
    const int colBase = blockIdx.x * 128;

    const int r16 = lane & 15;
    const int kg = lane >> 4;

    // staging: wave wid covers rows [wid*32, wid*32+32), 2 calls of 16 rows
    const int srow = (lane >> 2);          // 0..15 within call
    const int scol = (lane & 3) * 8;       // bf16 col chunk

    f32x4 acc[4][4];
#pragma unroll
    for (int m = 0; m < 4; ++m)
#pragma unroll
        for (int n = 0; n < 4; ++n) acc[m][n] = (f32x4)0.f;

    for (int k0 = 0; k0 < K; k0 += 32) {
#pragma unroll
        for (int c = 0; c < 2; ++c) {
            int r = wid * 32 + c * 16 + srow;
            stage16(&A[(size_t)(rowBase + r) * lda + k0 + scol],
                    &lA[(wid * 32 + c * 16) * 32]);
            stage16(&W[(size_t)(colBase + r) * ldw + k0 + scol],
                    &lW[(wid * 32 + c * 16) * 32]);
        }
        __syncthreads();

        short8 a[4], b[4];
#pragma unroll
        for (int m = 0; m < 4; ++m)
            a[m] = *(const short8*)&lA[(wr * 64 + m * 16 + r16) * 32 + kg * 8];
#pragma unroll
        for (int n = 0; n < 4; ++n)
            b[n] = *(const short8*)&lW[(wc * 64 + n * 16 + r16) * 32 + kg * 8];
#pragma unroll
        for (int m = 0; m < 4; ++m)
#pragma unroll
            for (int n = 0; n < 4; ++n)
                acc[m][n] = __builtin_amdgcn_mfma_f32_16x16x32_bf16(
                    a[m], b[n], acc[m][n], 0, 0, 0);
        __syncthreads();
    }

#pragma unroll
    for (int m = 0; m < 4; ++m) {
#pragma unroll
        for (int n = 0; n < 4; ++n) {
            int gc = colBase + wc * 64 + n * 16 + r16;
#pragma unroll
            for (int j = 0; j < 4; ++j) {
                int gr = rowBase + wr * 64 + m * 16 + kg * 4 + j;
                float v = acc[m][n][j];
                if (EPI == 2) {
                    if (isnan(v)) v = 0.f;
                    else if (isinf(v)) v = (v > 0.f) ? 1.f : -1.f;
                }
                C[(size_t)gr * ldc + gc] = v;
            }
        }
    }
}

// ---------------------------------------------------------------------------
// G4 split-K (global_load_lds staging, linear LDS)
// ---------------------------------------------------------------------------
__global__ __launch_bounds__(256) void g4_mfma(
    const bf16* __restrict__ A, const bf16* __restrict__ W,
    float* __restrict__ part)   // [2][2048][1024]
{
    const int kz = blockIdx.z;
    const int kOff = kz * 1024;
    float* C = part + (size_t)kz * 2048 * 1024;

    __shared__ bf16 lA[128 * 32];
    __shared__ bf16 lW[128 * 32];

    const int tid = threadIdx.x;
    const int lane = tid & 63;
    const int wid = tid >> 6;
    const int wr = wid >> 1;
    const int wc = wid & 1;
    const int rowBase = blockIdx.y * 128;
    const int colBase = blockIdx.x * 128;

    const int r16 = lane & 15;
    const int kg = lane >> 4;
    const int srow = (lane >> 2);
    const int scol = (lane & 3) * 8;

    f32x4 acc[4][4];
#pragma unroll
    for (int m = 0; m < 4; ++m)
#pragma unroll
        for (int n = 0; n < 4; ++n) acc[m][n] = (f32x4)0.f;

    for (int k0 = 0; k0 < 1024; k0 += 32) {
#pragma unroll
        for (int c = 0; c < 2; ++c) {
            int r = wid * 32 + c * 16 + srow;
            stage16(&A[(size_t)(rowBase + r) * 2048 + kOff + k0 + scol],
                    &lA[(wid * 32 + c * 16) * 32]);
            stage16(&W[(size_t)(colBase + r) * 2048 + kOff + k0 + scol],
                    &lW[(wid * 32 + c * 16) * 32]);
        }
        __syncthreads();

        short8 a[4], b[4];
#pragma unroll
        for (int m = 0; m < 4; ++m)
            a[m] = *(const short8*)&lA[(wr * 64 + m * 16 + r16) * 32 + kg * 8];
#pragma unroll
        for (int n = 0; n < 4; ++n)
            b[n] = *(const short8*)&lW[(wc * 64 + n * 16 + r16) * 32 + kg * 8];
#pragma unroll
        for (int m = 0; m < 4; ++m)
#pragma unroll
            for (int n = 0; n < 4; ++n)
                acc[m][n] = __builtin_amdgcn_mfma_f32_16x16x32_bf16(
                    a[m], b[n], acc[m][n], 0, 0, 0);
        __syncthreads();
    }

#pragma unroll
    for (int m = 0; m < 4; ++m) {
#pragma unroll
        for (int n = 0; n < 4; ++n) {
            int gc = colBase + wc * 64 + n * 16 + r16;
#pragma unroll
            for (int j = 0; j < 4; ++j) {
                int gr = rowBase + wr * 64 + m * 16 + kg * 4 + j;
                C[(size_t)gr * 1024 + gc] = acc[m][n][j];
            }
        }
    }
}

// g4_reduce: out = nan_to_num(p0 + p1)
__global__ __launch_bounds__(256) void g4_reduce(
    const float* __restrict__ part, float* __restrict__ out)
{
    int i = (blockIdx.x * 256 + threadIdx.x) * 4;
    float4 p0 = *(const float4*)&part[i];
    float4 p1 = *(const float4*)&part[2048 * 1024 + i];
    float r[4] = { p0.x + p1.x, p0.y + p1.y, p0.z + p1.z, p0.w + p1.w };
#pragma unroll
    for (int j = 0; j < 4; ++j) {
        float v = r[j];
        if (isnan(v)) v = 0.f;
        else if (isinf(v)) v = (v > 0.f) ? 1.f : -1.f;
        r[j] = v;
    }
    *(float4*)&out[i] = *(float4*)r;
}

// ---------------------------------------------------------------------------
// G3 as bf16 MFMA + dt epilogue (global_load_lds staging, K=64).
// ---------------------------------------------------------------------------
__global__ __launch_bounds__(256) void g3_mfma(
    const bf16* __restrict__ xdbl_bf,   // [2][2048][96]
    const bf16* __restrict__ dtw_bf,    // [2][2048][64]
    const float* __restrict__ biasf, const float* __restrict__ biasb,
    float* __restrict__ of, float* __restrict__ ob)
{
    const int dir = blockIdx.z;
    const bf16* A = xdbl_bf + (size_t)dir * 2048 * 96;
    const bf16* W = dtw_bf + (size_t)dir * 2048 * 64;
    const float* bias = dir ? biasb : biasf;
    float* C = dir ? ob : of;

    __shared__ bf16 lA[128 * 32];
    __shared__ bf16 lW[128 * 32];

    const int tid = threadIdx.x;
    const int lane = tid & 63;
    const int wid = tid >> 6;
    const int wr = wid >> 1;
    const int wc = wid & 1;
    const int rowBase = blockIdx.y * 128;
    const int colBase = blockIdx.x * 128;

    const int r16 = lane & 15;
    const int kg = lane >> 4;
    const int srow = (lane >> 2);
    const int scol = (lane & 3) * 8;

    f32x4 acc[4][4];
#pragma unroll
    for (int m = 0; m < 4; ++m)
#pragma unroll
        for (int n = 0; n < 4; ++n) acc[m][n] = (f32x4)0.f;

#pragma unroll
    for (int k0 = 0; k0 < 64; k0 += 32) {
#pragma unroll
        for (int c = 0; c < 2; ++c) {
            int r = wid * 32 + c * 16 + srow;
            stage16(&A[(size_t)(rowBase + r) * 96 + k0 + scol],
                    &lA[(wid * 32 + c * 16) * 32]);
            stage16(&W[(size_t)(colBase + r) * 64 + k0 + scol],
                    &lW[(wid * 32 + c * 16) * 32]);
        }
        __syncthreads();

        short8 a[4], b[4];
#pragma unroll
        for (int m = 0; m < 4; ++m)
            a[m] = *(const short8*)&lA[(wr * 64 + m * 16 + r16) * 32 + kg * 8];
#pragma unroll
        for (int n = 0; n < 4; ++n)
            b[n] = *(const short8*)&lW[(wc * 64 + n * 16 + r16) * 32 + kg * 8];
#pragma unroll
        for (int m = 0; m < 4; ++m)
#pragma unroll
            for (int n = 0; n < 4; ++n)
                acc[m][n] = __builtin_amdgcn_mfma_f32_16x16x32_bf16(
                    a[m], b[n], acc[m][n], 0, 0, 0);
        __syncthreads();
    }

#pragma unroll
    for (int m = 0; m < 4; ++m) {
#pragma unroll
        for (int n = 0; n < 4; ++n) {
            int gc = colBase + wc * 64 + n * 16 + r16;
            float bv = bias[gc];
#pragma unroll
            for (int j = 0; j < 4; ++j) {
                int gr = rowBase + wr * 64 + m * 16 + kg * 4 + j;
                float t = acc[m][n][j] + bv;
                t = fminf(fmaxf(t, 1e-5f), 1.0f);
                C[(size_t)gr * 2048 + gc] = softplusf(t + bv);
            }
        }
    }
}

// ---------------------------------------------------------------------------
// G2 as bf16 MFMA split-K (reg-staged; 96-row W tile doesn't fit wave-linear)
// ---------------------------------------------------------------------------
__global__ __launch_bounds__(256) void g2_mfma(
    const bf16* __restrict__ xcbf_f, const bf16* __restrict__ xcbf_b,
    const bf16* __restrict__ wxf, const bf16* __restrict__ wxb,
    float* __restrict__ part)   // [2][G2KS][2048][96]
{
    const int dir = blockIdx.z;
    const bf16* A = dir ? xcbf_b : xcbf_f;
    const bf16* W = dir ? wxb : wxf;
    const int rowBase = blockIdx.x * 128;
    const int kz = blockIdx.y;
    const int kBase = kz * (2048 / G2KS);

    __shared__ bf16 lA[128 * 40];
    __shared__ bf16 lW[96 * 40];

    const int tid = threadIdx.x;
    const int lane = tid & 63;
    const int wid = tid >> 6;
    const int r16 = lane & 15;
    const int kg = lane >> 4;

    f32x4 acc[2][6];
#pragma unroll
    for (int m = 0; m < 2; ++m)
#pragma unroll
        for (int n = 0; n < 6; ++n) acc[m][n] = (f32x4)0.f;

    const int srow = tid >> 2;
    const int scol = (tid & 3) * 8;

    for (int k0 = 0; k0 < 2048 / G2KS; k0 += 32) {
#pragma unroll
        for (int it = 0; it < 2; ++it) {
            int r = srow + it * 64;
            short8 va = *(const short8*)&A[(size_t)(rowBase + r) * 2048 + kBase + k0 + scol];
            *(short8*)&lA[r * 40 + scol] = va;
        }
        {
            short8 vw = *(const short8*)&W[(size_t)srow * 2048 + kBase + k0 + scol];
            *(short8*)&lW[srow * 40 + scol] = vw;
        }
        if (tid < 128) {
            int r = 64 + (tid >> 2);
            short8 vw2 = *(const short8*)&W[(size_t)r * 2048 + kBase + k0 + scol];
            *(short8*)&lW[r * 40 + scol] = vw2;
        }
        __syncthreads();

        short8 a[2], b[6];
#pragma unroll
        for (int m = 0; m < 2; ++m)
            a[m] = *(const short8*)&lA[(wid * 32 + m * 16 + r16) * 40 + kg * 8];
#pragma unroll
        for (int n = 0; n < 6; ++n)
            b[n] = *(const short8*)&lW[(n * 16 + r16) * 40 + kg * 8];
#pragma unroll
        for (int m = 0; m < 2; ++m)
#pragma unroll
            for (int n = 0; n < 6; ++n)
                acc[m][n] = __builtin_amdgcn_mfma_f32_16x16x32_bf16(
                    a[m], b[n], acc[m][n], 0, 0, 0);
        __syncthreads();
    }

    float* p = part + ((size_t)(dir * G2KS + kz) * 2048) * 96;
#pragma unroll
    for (int m = 0; m < 2; ++m) {
#pragma unroll
        for (int n = 0; n < 6; ++n) {
            int gc = n * 16 + r16;
#pragma unroll
            for (int j = 0; j < 4; ++j) {
                int gr = rowBase + wid * 32 + m * 16 + kg * 4 + j;
                p[(size_t)gr * 96 + gc] = acc[m][n][j];
            }
        }
    }
}

// g2_reduce: sum split-K partials -> fp32 xdbl AND bf16 xdbl copy (for g3)
__global__ __launch_bounds__(256) void g2_reduce(
    const float* __restrict__ part, float* __restrict__ xf, float* __restrict__ xb,
    bf16* __restrict__ xdbl_bf)
{
    int idx = blockIdx.x * 256 + threadIdx.x;
    int c = idx % 96;
    int r = (idx / 96) & 2047;
    int dir = idx / (96 * 2048);
    float s = 0.f;
#pragma unroll
    for (int ks = 0; ks < G2KS; ++ks)
        s += part[((size_t)(dir * G2KS + ks) * 2048 + r) * 96 + c];
    (dir ? xb : xf)[(size_t)r * 96 + c] = s;
    xdbl_bf[((size_t)dir * 2048 + r) * 96 + c] = __float2bfloat16(s);
}

// ---------------------------------------------------------------------------
// Fused f32 -> bf16 casts (all pre-G1 casts, one launch)
// ---------------------------------------------------------------------------
__global__ __launch_bounds__(256) void cast_all(
    const float* __restrict__ hidden, const float* __restrict__ in_proj_w,
    const float* __restrict__ xproj_w, const float* __restrict__ xproj_bw,
    const float* __restrict__ dtproj_w, const float* __restrict__ dtproj_bw,
    bf16* __restrict__ hbf, bf16* __restrict__ wbf,
    bf16* __restrict__ wxf, bf16* __restrict__ wxb,
    bf16* __restrict__ dtwf, bf16* __restrict__ dtwb)
{
    int bid = blockIdx.x;
    const float* src; bf16* dst; int base;
    if (bid < 1024)      { src = hidden;    dst = hbf;  base = bid; }
    else if (bid < 3072) { src = in_proj_w; dst = wbf;  base = bid - 1024; }
    else if (bid < 3168) { src = xproj_w;   dst = wxf;  base = bid - 3072; }
    else if (bid < 3264) { src = xproj_bw;  dst = wxb;  base = bid - 3168; }
    else if (bid < 3328) { src = dtproj_w;  dst = dtwf; base = bid - 3264; }
    else                 { src = dtproj_bw; dst = dtwb; base = bid - 3328; }
    int i = (base * 256 + threadIdx.x) * 8;
    float4 x = *(const float4*)&src[i];
    float4 y = *(const float4*)&src[i + 4];
    bf16 t[8] = { __float2bfloat16(x.x), __float2bfloat16(x.y),
                  __float2bfloat16(x.z), __float2bfloat16(x.w),
                  __float2bfloat16(y.x), __float2bfloat16(y.y),
                  __float2bfloat16(y.z), __float2bfloat16(y.w) };
    *(short8*)&dst[i] = *(short8*)t;
}

// ---------------------------------------------------------------------------
// Depthwise causal conv1d, 4 channels/thread (vectorized).
// ---------------------------------------------------------------------------
__global__ __launch_bounds__(256) void conv_kernel(
    const float* __restrict__ xz,
    const float* __restrict__ wf, const float* __restrict__ bf,
    const float* __restrict__ wb, const float* __restrict__ bb,
    float* __restrict__ xcf, float* __restrict__ xcb,
    bf16* __restrict__ xcbf, bf16* __restrict__ xcbb)
{
    int idx = blockIdx.x * 256 + threadIdx.x;
    int dg = idx & 511;
    int rest = idx >> 9;
    int l = rest & (LL - 1);
    int b = (rest >> 9) & (BB - 1);
    int dir = rest >> 11;
    int d0 = dg * 4;

    const float* w = dir ? wb : wf;
    const float* bias = dir ? bb : bf;

    float4 wv[4];
#pragma unroll
    for (int c = 0; c < 4; ++c)
        wv[c] = *(const float4*)&w[(d0 + c) * DCONV];

    float4 acc = *(const float4*)&bias[d0];
#pragma unroll
    for (int k = 0; k < DCONV; ++k) {
        int j = l - (DCONV - 1) + k;
        if (j >= 0) {
            int jj = dir ? (LL - 1 - j) : j;
            float4 x = *(const float4*)&xz[((size_t)(b * LL + jj)) * (2 * DINNER) + d0];
            acc.x += ((const float*)&wv[0])[k] * x.x;
            acc.y += ((const float*)&wv[1])[k] * x.y;
            acc.z += ((const float*)&wv[2])[k] * x.z;
            acc.w += ((const float*)&wv[3])[k] * x.w;
        }
    }

    size_t off = ((size_t)(b * LL + l)) * DINNER + d0;
    *(float4*)&((dir ? xcb : xcf)[off]) = acc;
    bf16 t[4] = { __float2bfloat16(acc.x), __float2bfloat16(acc.y),
                  __float2bfloat16(acc.z), __float2bfloat16(acc.w) };
    *(short4v*)&((dir ? xcbb : xcbf)[off]) = *(short4v*)t;
}

// ---------------------------------------------------------------------------
// Chunked scan phase 1 (arange-A fast path)
// ---------------------------------------------------------------------------
__global__ __launch_bounds__(256) void scan1_kernel(
    const float* __restrict__ Alog_f, const float* __restrict__ Alog_b,
    const float* __restrict__ xdbl_f, const float* __restrict__ xdbl_b,
    const float* __restrict__ xc_f, const float* __restrict__ xc_b,
    const float* __restrict__ dl_f, const float* __restrict__ dl_b,
    float* __restrict__ sdel, float* __restrict__ hend)
{
    const int tid = threadIdx.x;
    const int d = blockIdx.x * 256 + tid;
    const int c = blockIdx.y;
    const int z = blockIdx.z;           // dir*4 + b
    const int dir = z >> 2, b = z & 3;

    const float* Alog = dir ? Alog_b : Alog_f;
    const float* xdbl = dir ? xdbl_b : xdbl_f;
    const float* xc   = dir ? xc_b   : xc_f;
    const float* dl   = dir ? dl_b   : dl_f;
    const int rowBase = b * LL + c * SCHUNK;

    __shared__ float bs[SCHUNK][16];
#pragma unroll
    for (int i = 0; i < SCHUNK * 16 / 256; ++i) {
        int e = tid + 256 * i;
        int r = e >> 4, n = e & 15;
        bs[r][n] = xdbl[(size_t)(rowBase + r) * 96 + DTRANK + n];
    }
    __syncthreads();

    float Aa[DSTATE], h[DSTATE];
#pragma unroll
    for (int n = 0; n < DSTATE; ++n) {
        Aa[n] = -__expf(Alog[d * DSTATE + n]);
        h[n] = 0.f;
    }
    float sd = 0.f;
    const bool fast = a_is_arange(Aa);
    const float a0l2 = Aa[0] * 1.44269504f;

    float nxd = dl[(size_t)rowBase * DINNER + d];
    float nxu = xc[(size_t)rowBase * DINNER + d];

    if (fast) {
#pragma unroll 4
        for (int t = 0; t < SCHUNK; ++t) {
            float delta = nxd, u = nxu;
            if (t + 1 < SCHUNK) {
                size_t nrow = (size_t)(rowBase + t + 1);
                nxd = dl[nrow * DINNER + d];
                nxu = xc[nrow * DINNER + d];
            }
            u = fminf(fmaxf(u, -10.f), 10.f);
            float du = delta * u;
            sd += delta;
            float p[DSTATE];
            p[0] = exp2f(delta * a0l2);
#pragma unroll
            for (int n = 1; n < DSTATE; ++n)
                p[n] = p[n >> 1] * p[(n - 1) >> 1];
#pragma unroll
            for (int n = 0; n < DSTATE; ++n)
                h[n] = p[n] * h[n] + du * bs[t][n];
        }
    } else {
#pragma unroll 4
        for (int t = 0; t < SCHUNK; ++t) {
            float delta = nxd, u = nxu;
            if (t + 1 < SCHUNK) {
                size_t nrow = (size_t)(rowBase + t + 1);
                nxd = dl[nrow * DINNER + d];
                nxu = xc[nrow * DINNER + d];
            }
            u = fminf(fmaxf(u, -10.f), 10.f);
            float du = delta * u;
            sd += delta;
#pragma unroll
            for (int n = 0; n < DSTATE; ++n)
                h[n] = __expf(delta * Aa[n]) * h[n] + du * bs[t][n];
        }
    }

    size_t base = (size_t)z * SNC + c;
    sdel[base * DINNER + d] = sd;
#pragma unroll
    for (int n = 0; n < DSTATE; ++n)
        hend[(base * DSTATE + n) * DINNER + d] = h[n];
}

// ---------------------------------------------------------------------------
// Combine (n-parallel, IN PLACE)
// ---------------------------------------------------------------------------
__global__ __launch_bounds__(256) void scan_combine(
    const float* __restrict__ Alog_f, const float* __restrict__ Alog_b,
    const float* __restrict__ sdel, float* __restrict__ hend)
{
    int g = blockIdx.x * 256 + threadIdx.x;
    int d = g & (DINNER - 1);
    int n = (g >> 11) & (DSTATE - 1);
    int z = g >> 15;
    const float* Alog = (z >> 2) ? Alog_b : Alog_f;

    float Aa = -__expf(Alog[d * DSTATE + n]);
    float hr = 0.f;
    for (int c = 0; c < SNC; ++c) {
        size_t base = (size_t)z * SNC + c;
        size_t idx = (base * DSTATE + n) * DINNER + d;
        float he = hend[idx];
        hend[idx] = hr;
        float sd = sdel[base * DINNER + d];
        hr = __expf(sd * Aa) * hr + he;
    }
}

// ---------------------------------------------------------------------------
// Chunked scan phase 2 (arange-A fast path)
// ---------------------------------------------------------------------------
__global__ __launch_bounds__(256) void scan2_kernel(
    const float* __restrict__ Alog_f, const float* __restrict__ Alog_b,
    const float* __restrict__ Df, const float* __restrict__ Db,
    const float* __restrict__ xdbl_f, const float* __restrict__ xdbl_b,
    const float* __restrict__ xc_f, const float* __restrict__ xc_b,
    const float* __restrict__ hin,
    float* __restrict__ dl_f, float* __restrict__ dl_b)
{
    const int tid = threadIdx.x;
    const int d = blockIdx.x * 256 + tid;
    const int c = blockIdx.y;
    const int z = blockIdx.z;
    const int dir = z >> 2, b = z & 3;

    const float* Alog = dir ? Alog_b : Alog_f;
    const float* xdbl = dir ? xdbl_b : xdbl_f;
    const float* xc   = dir ? xc_b   : xc_f;
    float* dl         = dir ? dl_b   : dl_f;
    const int rowBase = b * LL + c * SCHUNK;

    __shared__ float bs[SCHUNK][32];
#pragma unroll
    for (int i = 0; i < SCHUNK * 32 / 256; ++i) {
        int e = tid + 256 * i;
        int r = e >> 5, n = e & 31;
        bs[r][n] = xdbl[(size_t)(rowBase + r) * 96 + DTRANK + n];
    }
    __syncthreads();

    float Dv = (dir ? Db : Df)[d];
    size_t base = (size_t)z * SNC + c;
    float Aa[DSTATE], h[DSTATE];
#pragma unroll
    for (int n = 0; n < DSTATE; ++n) {
        Aa[n] = -__expf(Alog[d * DSTATE + n]);
        h[n] = hin[(base * DSTATE + n) * DINNER + d];
    }
    const bool fast = a_is_arange(Aa);
    const float a0l2 = Aa[0] * 1.44269504f;

    float nxd = dl[(size_t)rowBase * DINNER + d];
    float nxu = xc[(size_t)rowBase * DINNER + d];

    if (fast) {
#pragma unroll 4
        for (int t = 0; t < SCHUNK; ++t) {
            float delta = nxd, u = nxu;
            if (t + 1 < SCHUNK) {
                size_t nrow = (size_t)(rowBase + t + 1);
                nxd = dl[nrow * DINNER + d];
                nxu = xc[nrow * DINNER + d];
            }
            u = fminf(fmaxf(u, -10.f), 10.f);
            float du = delta * u;
            float p[DSTATE];
            p[0] = exp2f(delta * a0l2);
#pragma unroll
            for (int n = 1; n < DSTATE; ++n)
                p[n] = p[n >> 1] * p[(n - 1) >> 1];
            float y = 0.f;
#pragma unroll
            for (int n = 0; n < DSTATE; ++n) {
                h[n] = p[n] * h[n] + du * bs[t][n];
                y += h[n] * bs[t][DSTATE + n];
            }
            dl[(size_t)(rowBase + t) * DINNER + d] = y + u * Dv;
        }
    } else {
#pragma unroll 4
        for (int t = 0; t < SCHUNK; ++t) {
            float delta = nxd, u = nxu;
            if (t + 1 < SCHUNK) {
                size_t nrow = (size_t)(rowBase + t + 1);
                nxd = dl[nrow * DINNER + d];
                nxu = xc[nrow * DINNER + d];
            }
            u = fminf(fmaxf(u, -10.f), 10.f);
            float du = delta * u;
            float y = 0.f;
#pragma unroll
            for (int n = 0; n < DSTATE; ++n) {
                h[n] = __expf(delta * Aa[n]) * h[n] + du * bs[t][n];
                y += h[n] * bs[t][DSTATE + n];
            }
            dl[(size_t)(rowBase + t) * DINNER + d] = y + u * Dv;
        }
    }
}

// ---------------------------------------------------------------------------
// Gate + out_pw cast fused
// ---------------------------------------------------------------------------
__global__ __launch_bounds__(256) void gate_cast(
    const float* __restrict__ yf, const float* __restrict__ yb,
    const float* __restrict__ xz, bf16* __restrict__ ytot,
    const float* __restrict__ out_pw, bf16* __restrict__ obf)
{
    int bid = blockIdx.x;
    if (bid < 16384) {
        int idx = bid * 256 + threadIdx.x;
        int d = idx & (DINNER - 1);
        int l = (idx >> 11) & (LL - 1);
        int b = idx >> 20;
        size_t rowf = (size_t)(b * LL + l);
        size_t rowb = (size_t)(b * LL + (LL - 1 - l));
        float y = yf[rowf * DINNER + d] + yb[rowb * DINNER + d];
        float z = xz[rowf * (2 * DINNER) + DINNER + d];
        float s = z / (1.f + __expf(-z));
        ytot[rowf * DINNER + d] = __float2bfloat16(y * s);
    } else {
        int i = ((bid - 16384) * 256 + threadIdx.x) * 8;
        float4 x = *(const float4*)&out_pw[i];
        float4 y = *(const float4*)&out_pw[i + 4];
        bf16 t[8] = { __float2bfloat16(x.x), __float2bfloat16(x.y),
                      __float2bfloat16(x.z), __float2bfloat16(x.w),
                      __float2bfloat16(y.x), __float2bfloat16(y.y),
                      __float2bfloat16(y.z), __float2bfloat16(y.w) };
        *(short8*)&obf[i] = *(short8*)t;
    }
}

// ---------------------------------------------------------------------------
extern "C" void kernel_launch(void* const* d_in, const int* in_sizes, int n_in,
                              void* d_out, int out_size, void* d_ws, size_t ws_size,
                              hipStream_t stream)
{
    const float* hidden    = (const float*)d_in[0];
    const float* in_proj_w = (const float*)d_in[1];
    const float* conv_w    = (const float*)d_in[2];
    const float* conv_b    = (const float*)d_in[3];
    const float* xproj_w   = (const float*)d_in[4];
    const float* dtproj_w  = (const float*)d_in[5];
    const float* dtproj_b  = (const float*)d_in[6];
    const float* A_log     = (const float*)d_in[7];
    const float* Dvec      = (const float*)d_in[8];
    const float* conv_bw   = (const float*)d_in[9];
    const float* conv_bb   = (const float*)d_in[10];
    const float* xproj_bw  = (const float*)d_in[11];
    const float* dtproj_bw = (const float*)d_in[12];
    const float* dtproj_bb = (const float*)d_in[13];
    const float* A_b_log   = (const float*)d_in[14];
    const float* D_b       = (const float*)d_in[15];
    const float* out_pw    = (const float*)d_in[16];
    float* out = (float*)d_out;

    // Workspace layout (f32 elements). Total 31,916,032 = 127.7 MB.
    float* ws = (float*)d_ws;
    float* xz      = ws;                       // 8388608
    float* xc_f    = xz + 8388608;             // 4194304
    float* xc_b    = xc_f + 4194304;           // 4194304
    float* xdbl_f  = xc_b + 4194304;           // 196608
    float* xdbl_b  = xdbl_f + 196608;          // 196608
    float* dl_f    = xdbl_b + 196608;          // 4194304 (delta -> y)
    float* dl_b    = dl_f + 4194304;           // 4194304
    float* g2part  = dl_b + 4194304;           // 1572864
    float* sdel    = g2part + 1572864;         // 262144
    float* hend    = sdel + 262144;            // 4194304; becomes hin in place
    float* smallb  = hend + 4194304;           // 327680

    // bf16 aliases over regions dead at time of use:
    bf16* hbf = (bf16*)dl_f;
    bf16* wbf = (bf16*)(dl_f + 1048576);
    bf16* wxf = (bf16*)dl_b;
    bf16* wxb = (bf16*)(dl_b + 98304);
    bf16* xcbf = (bf16*)hend;
    bf16* xcbb = (bf16*)(hend + 2097152);
    bf16* xdbl_bf = (bf16*)smallb;
    bf16* dtw_bf  = (bf16*)(smallb + 196608);
    bf16* ytot_bf = (bf16*)xc_f;
    bf16* obf = (bf16*)xc_b;
    float* g4part = dl_f;

    dim3 blk(256);

    // all pre-G1 casts in one launch
    cast_all<<<dim3(3392), blk, 0, stream>>>(
        hidden, in_proj_w, xproj_w, xproj_bw, dtproj_w, dtproj_bw,
        hbf, wbf, wxf, wxb, dtw_bf, dtw_bf + 131072);

    // G1: xz = hidden @ in_proj_w.T   (M=2048, N=4096, K=1024) bf16 MFMA
    gemm_bf16<0><<<dim3(4096 / 128, MROWS / 128), blk, 0, stream>>>(
        hbf, wbf, xz, 4096, 1024, 1024, 1024, 4096);

    // conv both dirs, 4 channels/thread (fp32 + bf16 outputs)
    conv_kernel<<<dim3(2 * BB * LL * DINNER / 4 / 256), blk, 0, stream>>>(
        xz, conv_w, conv_b, conv_bw, conv_bb, xc_f, xc_b, xcbf, xcbb);

    // G2 via bf16 MFMA split-K
    g2_mfma<<<dim3(16, G2KS, 2), blk, 0, stream>>>(
        xcbf, xcbb, wxf, wxb, g2part);
    g2_reduce<<<dim3(2 * 2048 * 96 / 256), blk, 0, stream>>>(
        g2part, xdbl_f, xdbl_b, xdbl_bf);

    // G3 via bf16 MFMA (both dirs)
    g3_mfma<<<dim3(16, 16, 2), blk, 0, stream>>>(
        xdbl_bf, dtw_bf, dtproj_b, dtproj_bb, dl_f, dl_b);

    // chunked scan (SCHUNK=32, in-place combine, arange-A fast path)
    scan1_kernel<<<dim3(DINNER / 256, SNC, 8), blk, 0, stream>>>(
        A_log, A_b_log, xdbl_f, xdbl_b, xc_f, xc_b, dl_f, dl_b, sdel, hend);
    scan_combine<<<dim3(2 * BB * DSTATE * DINNER / 256), blk, 0, stream>>>(
        A_log, A_b_log, sdel, hend);
    scan2_kernel<<<dim3(DINNER / 256, SNC, 8), blk, 0, stream>>>(
        A_log, A_b_log, Dvec, D_b, xdbl_f, xdbl_b, xc_f, xc_b, hend, dl_f, dl_b);

    // gate -> bf16 ytot, + out_pw cast (fused)
    gate_cast<<<dim3(16384 + 1024), blk, 0, stream>>>(
        dl_f, dl_b, xz, ytot_bf, out_pw, obf);

    // G4 split-K=2 + fused reduce/nan_to_num
    g4_mfma<<<dim3(1024 / 128, MROWS / 128, 2), blk, 0, stream>>>(
        ytot_bf, obf, g4part);
    g4_reduce<<<dim3(2048 * 1024 / 4 / 256), blk, 0, stream>>>(g4part, out);
}

// Round 14
// 219.252 us; speedup vs baseline: 1.0259x; 1.0259x over previous
//
#include <hip/hip_runtime.h>
#include <hip/hip_bf16.h>
#include <math.h>

// Problem constants
#define BB 4
#define LL 512
#define DMODEL 1024
#define DSTATE 16
#define DCONV 4
#define DINNER 2048
#define DTRANK 64
#define MROWS (BB*LL)          // 2048 rows of (b,l)
#define G2KS 4                 // split-K factor for the N=96 GEMM
#define SCHUNK 32              // scan chunk length
#define SNC (LL / SCHUNK)      // 16 chunks

typedef __hip_bfloat16 bf16;
typedef __attribute__((ext_vector_type(8))) short short8;
typedef __attribute__((ext_vector_type(4))) short short4v;
typedef __attribute__((ext_vector_type(4))) float f32x4;

__device__ __forceinline__ float softplusf(float x) {
    return x > 20.f ? x : log1pf(__expf(x));
}

// Async global->LDS, 16B per lane (wave-uniform LDS base, per-lane global src)
__device__ __forceinline__ void stage16(const void* g, void* l) {
    __builtin_amdgcn_global_load_lds(
        (const __attribute__((address_space(1))) void*)g,
        (__attribute__((address_space(3))) void*)l, 16, 0, 0);
}

// A has the Vim structure Aa[n] == (n+1)*Aa[0]?
__device__ __forceinline__ bool a_is_arange(const float* Aa) {
    bool ok = true;
#pragma unroll
    for (int n = 1; n < DSTATE; ++n) {
        float k = (float)(n + 1);
        ok = ok && (fabsf(Aa[n] - k * Aa[0]) <= 1e-4f * k * fabsf(Aa[0]));
    }
    return ok;
}

// ---------------------------------------------------------------------------
// bf16 MFMA TN GEMM (linear LDS + global_load_lds). EPI 0: none; 2: nan_to_num
// ---------------------------------------------------------------------------
template<int EPI>
__global__ __launch_bounds__(256) void gemm_bf16(
    const bf16* __restrict__ A, const bf16* __restrict__ W,
    float* __restrict__ C, int N, int K, int lda, int ldw, int ldc)
{
    __shared__ bf16 lA[128 * 32];
    __shared__ bf16 lW[128 * 32];

    const int tid = threadIdx.x;
    const int lane = tid & 63;
    const int wid = tid >> 6;
    const int wr = wid >> 1;
    const int wc = wid & 1;
    const int rowBase = blockIdx.y * 128;
    const int colBase = blockIdx.x * 128;

    const int r16 = lane & 15;
    const int kg = lane >> 4;
    const int srow = (lane >> 2);
    const int scol = (lane & 3) * 8;

    f32x4 acc[4][4];
#pragma unroll
    for (int m = 0; m < 4; ++m)
#pragma unroll
        for (int n = 0; n < 4; ++n) acc[m][n] = (f32x4)0.f;

    for (int k0 = 0; k0 < K; k0 += 32) {
#pragma unroll
        for (int c = 0; c < 2; ++c) {
            int r = wid * 32 + c * 16 + srow;
            stage16(&A[(size_t)(rowBase + r) * lda + k0 + scol],
                    &lA[(wid * 32 + c * 16) * 32]);
            stage16(&W[(size_t)(colBase + r) * ldw + k0 + scol],
                    &lW[(wid * 32 + c * 16) * 32]);
        }
        __syncthreads();

        short8 a[4], b[4];
#pragma unroll
        for (int m = 0; m < 4; ++m)
            a[m] = *(const short8*)&lA[(wr * 64 + m * 16 + r16) * 32 + kg * 8];
#pragma unroll
        for (int n = 0; n < 4; ++n)
            b[n] = *(const short8*)&lW[(wc * 64 + n * 16 + r16) * 32 + kg * 8];
#pragma unroll
        for (int m = 0; m < 4; ++m)
#pragma unroll
            for (int n = 0; n < 4; ++n)
                acc[m][n] = __builtin_amdgcn_mfma_f32_16x16x32_bf16(
                    a[m], b[n], acc[m][n], 0, 0, 0);
        __syncthreads();
    }

#pragma unroll
    for (int m = 0; m < 4; ++m) {
#pragma unroll
        for (int n = 0; n < 4; ++n) {
            int gc = colBase + wc * 64 + n * 16 + r16;
#pragma unroll
            for (int j = 0; j < 4; ++j) {
                int gr = rowBase + wr * 64 + m * 16 + kg * 4 + j;
                float v = acc[m][n][j];
                if (EPI == 2) {
                    if (isnan(v)) v = 0.f;
                    else if (isinf(v)) v = (v > 0.f) ? 1.f : -1.f;
                }
                C[(size_t)gr * ldc + gc] = v;
            }
        }
    }
}

// ---------------------------------------------------------------------------
// G4 split-K (global_load_lds staging)
// ---------------------------------------------------------------------------
__global__ __launch_bounds__(256) void g4_mfma(
    const bf16* __restrict__ A, const bf16* __restrict__ W,
    float* __restrict__ part)   // [2][2048][1024]
{
    const int kz = blockIdx.z;
    const int kOff = kz * 1024;
    float* C = part + (size_t)kz * 2048 * 1024;

    __shared__ bf16 lA[128 * 32];
    __shared__ bf16 lW[128 * 32];

    const int tid = threadIdx.x;
    const int lane = tid & 63;
    const int wid = tid >> 6;
    const int wr = wid >> 1;
    const int wc = wid & 1;
    const int rowBase = blockIdx.y * 128;
    const int colBase = blockIdx.x * 128;

    const int r16 = lane & 15;
    const int kg = lane >> 4;
    const int srow = (lane >> 2);
    const int scol = (lane & 3) * 8;

    f32x4 acc[4][4];
#pragma unroll
    for (int m = 0; m < 4; ++m)
#pragma unroll
        for (int n = 0; n < 4; ++n) acc[m][n] = (f32x4)0.f;

    for (int k0 = 0; k0 < 1024; k0 += 32) {
#pragma unroll
        for (int c = 0; c < 2; ++c) {
            int r = wid * 32 + c * 16 + srow;
            stage16(&A[(size_t)(rowBase + r) * 2048 + kOff + k0 + scol],
                    &lA[(wid * 32 + c * 16) * 32]);
            stage16(&W[(size_t)(colBase + r) * 2048 + kOff + k0 + scol],
                    &lW[(wid * 32 + c * 16) * 32]);
        }
        __syncthreads();

        short8 a[4], b[4];
#pragma unroll
        for (int m = 0; m < 4; ++m)
            a[m] = *(const short8*)&lA[(wr * 64 + m * 16 + r16) * 32 + kg * 8];
#pragma unroll
        for (int n = 0; n < 4; ++n)
            b[n] = *(const short8*)&lW[(wc * 64 + n * 16 + r16) * 32 + kg * 8];
#pragma unroll
        for (int m = 0; m < 4; ++m)
#pragma unroll
            for (int n = 0; n < 4; ++n)
                acc[m][n] = __builtin_amdgcn_mfma_f32_16x16x32_bf16(
                    a[m], b[n], acc[m][n], 0, 0, 0);
        __syncthreads();
    }

#pragma unroll
    for (int m = 0; m < 4; ++m) {
#pragma unroll
        for (int n = 0; n < 4; ++n) {
            int gc = colBase + wc * 64 + n * 16 + r16;
#pragma unroll
            for (int j = 0; j < 4; ++j) {
                int gr = rowBase + wr * 64 + m * 16 + kg * 4 + j;
                C[(size_t)gr * 1024 + gc] = acc[m][n][j];
            }
        }
    }
}

// g4_reduce: out = nan_to_num(p0 + p1)
__global__ __launch_bounds__(256) void g4_reduce(
    const float* __restrict__ part, float* __restrict__ out)
{
    int i = (blockIdx.x * 256 + threadIdx.x) * 4;
    float4 p0 = *(const float4*)&part[i];
    float4 p1 = *(const float4*)&part[2048 * 1024 + i];
    float r[4] = { p0.x + p1.x, p0.y + p1.y, p0.z + p1.z, p0.w + p1.w };
#pragma unroll
    for (int j = 0; j < 4; ++j) {
        float v = r[j];
        if (isnan(v)) v = 0.f;
        else if (isinf(v)) v = (v > 0.f) ? 1.f : -1.f;
        r[j] = v;
    }
    *(float4*)&out[i] = *(float4*)r;
}

// ---------------------------------------------------------------------------
// G3 as bf16 MFMA + dt epilogue -> bf16 delta output.
// ---------------------------------------------------------------------------
__global__ __launch_bounds__(256) void g3_mfma(
    const bf16* __restrict__ xdbl_bf,   // [2][2048][96]
    const bf16* __restrict__ dtw_bf,    // [2][2048][64]
    const float* __restrict__ biasf, const float* __restrict__ biasb,
    bf16* __restrict__ of, bf16* __restrict__ ob)
{
    const int dir = blockIdx.z;
    const bf16* A = xdbl_bf + (size_t)dir * 2048 * 96;
    const bf16* W = dtw_bf + (size_t)dir * 2048 * 64;
    const float* bias = dir ? biasb : biasf;
    bf16* C = dir ? ob : of;

    __shared__ bf16 lA[128 * 32];
    __shared__ bf16 lW[128 * 32];

    const int tid = threadIdx.x;
    const int lane = tid & 63;
    const int wid = tid >> 6;
    const int wr = wid >> 1;
    const int wc = wid & 1;
    const int rowBase = blockIdx.y * 128;
    const int colBase = blockIdx.x * 128;

    const int r16 = lane & 15;
    const int kg = lane >> 4;
    const int srow = (lane >> 2);
    const int scol = (lane & 3) * 8;

    f32x4 acc[4][4];
#pragma unroll
    for (int m = 0; m < 4; ++m)
#pragma unroll
        for (int n = 0; n < 4; ++n) acc[m][n] = (f32x4)0.f;

#pragma unroll
    for (int k0 = 0; k0 < 64; k0 += 32) {
#pragma unroll
        for (int c = 0; c < 2; ++c) {
            int r = wid * 32 + c * 16 + srow;
            stage16(&A[(size_t)(rowBase + r) * 96 + k0 + scol],
                    &lA[(wid * 32 + c * 16) * 32]);
            stage16(&W[(size_t)(colBase + r) * 64 + k0 + scol],
                    &lW[(wid * 32 + c * 16) * 32]);
        }
        __syncthreads();

        short8 a[4], b[4];
#pragma unroll
        for (int m = 0; m < 4; ++m)
            a[m] = *(const short8*)&lA[(wr * 64 + m * 16 + r16) * 32 + kg * 8];
#pragma unroll
        for (int n = 0; n < 4; ++n)
            b[n] = *(const short8*)&lW[(wc * 64 + n * 16 + r16) * 32 + kg * 8];
#pragma unroll
        for (int m = 0; m < 4; ++m)
#pragma unroll
            for (int n = 0; n < 4; ++n)
                acc[m][n] = __builtin_amdgcn_mfma_f32_16x16x32_bf16(
                    a[m], b[n], acc[m][n], 0, 0, 0);
        __syncthreads();
    }

#pragma unroll
    for (int m = 0; m < 4; ++m) {
#pragma unroll
        for (int n = 0; n < 4; ++n) {
            int gc = colBase + wc * 64 + n * 16 + r16;
            float bv = bias[gc];
#pragma unroll
            for (int j = 0; j < 4; ++j) {
                int gr = rowBase + wr * 64 + m * 16 + kg * 4 + j;
                float t = acc[m][n][j] + bv;
                t = fminf(fmaxf(t, 1e-5f), 1.0f);
                C[(size_t)gr * 2048 + gc] = __float2bfloat16(softplusf(t + bv));
            }
        }
    }
}

// ---------------------------------------------------------------------------
// G2 as bf16 MFMA split-K (reg-staged)
// ---------------------------------------------------------------------------
__global__ __launch_bounds__(256) void g2_mfma(
    const bf16* __restrict__ xcbf_f, const bf16* __restrict__ xcbf_b,
    const bf16* __restrict__ wxf, const bf16* __restrict__ wxb,
    float* __restrict__ part)   // [2][G2KS][2048][96]
{
    const int dir = blockIdx.z;
    const bf16* A = dir ? xcbf_b : xcbf_f;
    const bf16* W = dir ? wxb : wxf;
    const int rowBase = blockIdx.x * 128;
    const int kz = blockIdx.y;
    const int kBase = kz * (2048 / G2KS);

    __shared__ bf16 lA[128 * 40];
    __shared__ bf16 lW[96 * 40];

    const int tid = threadIdx.x;
    const int lane = tid & 63;
    const int wid = tid >> 6;
    const int r16 = lane & 15;
    const int kg = lane >> 4;

    f32x4 acc[2][6];
#pragma unroll
    for (int m = 0; m < 2; ++m)
#pragma unroll
        for (int n = 0; n < 6; ++n) acc[m][n] = (f32x4)0.f;

    const int srow = tid >> 2;
    const int scol = (tid & 3) * 8;

    for (int k0 = 0; k0 < 2048 / G2KS; k0 += 32) {
#pragma unroll
        for (int it = 0; it < 2; ++it) {
            int r = srow + it * 64;
            short8 va = *(const short8*)&A[(size_t)(rowBase + r) * 2048 + kBase + k0 + scol];
            *(short8*)&lA[r * 40 + scol] = va;
        }
        {
            short8 vw = *(const short8*)&W[(size_t)srow * 2048 + kBase + k0 + scol];
            *(short8*)&lW[srow * 40 + scol] = vw;
        }
        if (tid < 128) {
            int r = 64 + (tid >> 2);
            short8 vw2 = *(const short8*)&W[(size_t)r * 2048 + kBase + k0 + scol];
            *(short8*)&lW[r * 40 + scol] = vw2;
        }
        __syncthreads();

        short8 a[2], b[6];
#pragma unroll
        for (int m = 0; m < 2; ++m)
            a[m] = *(const short8*)&lA[(wid * 32 + m * 16 + r16) * 40 + kg * 8];
#pragma unroll
        for (int n = 0; n < 6; ++n)
            b[n] = *(const short8*)&lW[(n * 16 + r16) * 40 + kg * 8];
#pragma unroll
        for (int m = 0; m < 2; ++m)
#pragma unroll
            for (int n = 0; n < 6; ++n)
                acc[m][n] = __builtin_amdgcn_mfma_f32_16x16x32_bf16(
                    a[m], b[n], acc[m][n], 0, 0, 0);
        __syncthreads();
    }

    float* p = part + ((size_t)(dir * G2KS + kz) * 2048) * 96;
#pragma unroll
    for (int m = 0; m < 2; ++m) {
#pragma unroll
        for (int n = 0; n < 6; ++n) {
            int gc = n * 16 + r16;
#pragma unroll
            for (int j = 0; j < 4; ++j) {
                int gr = rowBase + wid * 32 + m * 16 + kg * 4 + j;
                p[(size_t)gr * 96 + gc] = acc[m][n][j];
            }
        }
    }
}

// g2_reduce: sum split-K partials -> fp32 xdbl AND bf16 xdbl copy (for g3)
__global__ __launch_bounds__(256) void g2_reduce(
    const float* __restrict__ part, float* __restrict__ xf, float* __restrict__ xb,
    bf16* __restrict__ xdbl_bf)
{
    int idx = blockIdx.x * 256 + threadIdx.x;
    int c = idx % 96;
    int r = (idx / 96) & 2047;
    int dir = idx / (96 * 2048);
    float s = 0.f;
#pragma unroll
    for (int ks = 0; ks < G2KS; ++ks)
        s += part[((size_t)(dir * G2KS + ks) * 2048 + r) * 96 + c];
    (dir ? xb : xf)[(size_t)r * 96 + c] = s;
    xdbl_bf[((size_t)dir * 2048 + r) * 96 + c] = __float2bfloat16(s);
}

// ---------------------------------------------------------------------------
// Fused f32 -> bf16 casts (all pre-G1 casts, one launch)
// ---------------------------------------------------------------------------
__global__ __launch_bounds__(256) void cast_all(
    const float* __restrict__ hidden, const float* __restrict__ in_proj_w,
    const float* __restrict__ xproj_w, const float* __restrict__ xproj_bw,
    const float* __restrict__ dtproj_w, const float* __restrict__ dtproj_bw,
    bf16* __restrict__ hbf, bf16* __restrict__ wbf,
    bf16* __restrict__ wxf, bf16* __restrict__ wxb,
    bf16* __restrict__ dtwf, bf16* __restrict__ dtwb)
{
    int bid = blockIdx.x;
    const float* src; bf16* dst; int base;
    if (bid < 1024)      { src = hidden;    dst = hbf;  base = bid; }
    else if (bid < 3072) { src = in_proj_w; dst = wbf;  base = bid - 1024; }
    else if (bid < 3168) { src = xproj_w;   dst = wxf;  base = bid - 3072; }
    else if (bid < 3264) { src = xproj_bw;  dst = wxb;  base = bid - 3168; }
    else if (bid < 3328) { src = dtproj_w;  dst = dtwf; base = bid - 3264; }
    else                 { src = dtproj_bw; dst = dtwb; base = bid - 3328; }
    int i = (base * 256 + threadIdx.x) * 8;
    float4 x = *(const float4*)&src[i];
    float4 y = *(const float4*)&src[i + 4];
    bf16 t[8] = { __float2bfloat16(x.x), __float2bfloat16(x.y),
                  __float2bfloat16(x.z), __float2bfloat16(x.w),
                  __float2bfloat16(y.x), __float2bfloat16(y.y),
                  __float2bfloat16(y.z), __float2bfloat16(y.w) };
    *(short8*)&dst[i] = *(short8*)t;
}

// ---------------------------------------------------------------------------
// Depthwise causal conv1d, 4 channels/thread. Output: bf16 xc only.
// ---------------------------------------------------------------------------
__global__ __launch_bounds__(256) void conv_kernel(
    const float* __restrict__ xz,
    const float* __restrict__ wf, const float* __restrict__ bf,
    const float* __restrict__ wb, const float* __restrict__ bb,
    bf16* __restrict__ xcbf, bf16* __restrict__ xcbb)
{
    int idx = blockIdx.x * 256 + threadIdx.x;
    int dg = idx & 511;
    int rest = idx >> 9;
    int l = rest & (LL - 1);
    int b = (rest >> 9) & (BB - 1);
    int dir = rest >> 11;
    int d0 = dg * 4;

    const float* w = dir ? wb : wf;
    const float* bias = dir ? bb : bf;

    float4 wv[4];
#pragma unroll
    for (int c = 0; c < 4; ++c)
        wv[c] = *(const float4*)&w[(d0 + c) * DCONV];

    float4 acc = *(const float4*)&bias[d0];
#pragma unroll
    for (int k = 0; k < DCONV; ++k) {
        int j = l - (DCONV - 1) + k;
        if (j >= 0) {
            int jj = dir ? (LL - 1 - j) : j;
            float4 x = *(const float4*)&xz[((size_t)(b * LL + jj)) * (2 * DINNER) + d0];
            acc.x += ((const float*)&wv[0])[k] * x.x;
            acc.y += ((const float*)&wv[1])[k] * x.y;
            acc.z += ((const float*)&wv[2])[k] * x.z;
            acc.w += ((const float*)&wv[3])[k] * x.w;
        }
    }

    size_t off = ((size_t)(b * LL + l)) * DINNER + d0;
    bf16 t[4] = { __float2bfloat16(acc.x), __float2bfloat16(acc.y),
                  __float2bfloat16(acc.z), __float2bfloat16(acc.w) };
    *(short4v*)&((dir ? xcbb : xcbf)[off]) = *(short4v*)t;
}

// ---------------------------------------------------------------------------
// Chunked scan phase 1 (bf16 delta/u inputs, arange-A fast path)
// ---------------------------------------------------------------------------
__global__ __launch_bounds__(256) void scan1_kernel(
    const float* __restrict__ Alog_f, const float* __restrict__ Alog_b,
    const float* __restrict__ xdbl_f, const float* __restrict__ xdbl_b,
    const bf16* __restrict__ xc_f, const bf16* __restrict__ xc_b,
    const bf16* __restrict__ dl_f, const bf16* __restrict__ dl_b,
    float* __restrict__ sdel, float* __restrict__ hend)
{
    const int tid = threadIdx.x;
    const int d = blockIdx.x * 256 + tid;
    const int c = blockIdx.y;
    const int z = blockIdx.z;           // dir*4 + b
    const int dir = z >> 2, b = z & 3;

    const float* Alog = dir ? Alog_b : Alog_f;
    const float* xdbl = dir ? xdbl_b : xdbl_f;
    const bf16* xc    = dir ? xc_b   : xc_f;
    const bf16* dl    = dir ? dl_b   : dl_f;
    const int rowBase = b * LL + c * SCHUNK;

    __shared__ float bs[SCHUNK][16];
#pragma unroll
    for (int i = 0; i < SCHUNK * 16 / 256; ++i) {
        int e = tid + 256 * i;
        int r = e >> 4, n = e & 15;
        bs[r][n] = xdbl[(size_t)(rowBase + r) * 96 + DTRANK + n];
    }
    __syncthreads();

    float Aa[DSTATE], h[DSTATE];
#pragma unroll
    for (int n = 0; n < DSTATE; ++n) {
        Aa[n] = -__expf(Alog[d * DSTATE + n]);
        h[n] = 0.f;
    }
    float sd = 0.f;
    const bool fast = a_is_arange(Aa);
    const float a0l2 = Aa[0] * 1.44269504f;

    float nxd = __bfloat162float(dl[(size_t)rowBase * DINNER + d]);
    float nxu = __bfloat162float(xc[(size_t)rowBase * DINNER + d]);

    if (fast) {
#pragma unroll 4
        for (int t = 0; t < SCHUNK; ++t) {
            float delta = nxd, u = nxu;
            if (t + 1 < SCHUNK) {
                size_t nrow = (size_t)(rowBase + t + 1);
                nxd = __bfloat162float(dl[nrow * DINNER + d]);
                nxu = __bfloat162float(xc[nrow * DINNER + d]);
            }
            u = fminf(fmaxf(u, -10.f), 10.f);
            float du = delta * u;
            sd += delta;
            float p[DSTATE];
            p[0] = exp2f(delta * a0l2);
#pragma unroll
            for (int n = 1; n < DSTATE; ++n)
                p[n] = p[n >> 1] * p[(n - 1) >> 1];
#pragma unroll
            for (int n = 0; n < DSTATE; ++n)
                h[n] = p[n] * h[n] + du * bs[t][n];
        }
    } else {
#pragma unroll 4
        for (int t = 0; t < SCHUNK; ++t) {
            float delta = nxd, u = nxu;
            if (t + 1 < SCHUNK) {
                size_t nrow = (size_t)(rowBase + t + 1);
                nxd = __bfloat162float(dl[nrow * DINNER + d]);
                nxu = __bfloat162float(xc[nrow * DINNER + d]);
            }
            u = fminf(fmaxf(u, -10.f), 10.f);
            float du = delta * u;
            sd += delta;
#pragma unroll
            for (int n = 0; n < DSTATE; ++n)
                h[n] = __expf(delta * Aa[n]) * h[n] + du * bs[t][n];
        }
    }

    size_t base = (size_t)z * SNC + c;
    sdel[base * DINNER + d] = sd;
#pragma unroll
    for (int n = 0; n < DSTATE; ++n)
        hend[(base * DSTATE + n) * DINNER + d] = h[n];
}

// ---------------------------------------------------------------------------
// Combine (n-parallel, IN PLACE)
// ---------------------------------------------------------------------------
__global__ __launch_bounds__(256) void scan_combine(
    const float* __restrict__ Alog_f, const float* __restrict__ Alog_b,
    const float* __restrict__ sdel, float* __restrict__ hend)
{
    int g = blockIdx.x * 256 + threadIdx.x;
    int d = g & (DINNER - 1);
    int n = (g >> 11) & (DSTATE - 1);
    int z = g >> 15;
    const float* Alog = (z >> 2) ? Alog_b : Alog_f;

    float Aa = -__expf(Alog[d * DSTATE + n]);
    float hr = 0.f;
    for (int c = 0; c < SNC; ++c) {
        size_t base = (size_t)z * SNC + c;
        size_t idx = (base * DSTATE + n) * DINNER + d;
        float he = hend[idx];
        hend[idx] = hr;
        float sd = sdel[base * DINNER + d];
        hr = __expf(sd * Aa) * hr + he;
    }
}

// ---------------------------------------------------------------------------
// Chunked scan phase 2 (bf16 in, bf16 y out in place, arange-A fast path)
// ---------------------------------------------------------------------------
__global__ __launch_bounds__(256) void scan2_kernel(
    const float* __restrict__ Alog_f, const float* __restrict__ Alog_b,
    const float* __restrict__ Df, const float* __restrict__ Db,
    const float* __restrict__ xdbl_f, const float* __restrict__ xdbl_b,
    const bf16* __restrict__ xc_f, const bf16* __restrict__ xc_b,
    const float* __restrict__ hin,
    bf16* __restrict__ dl_f, bf16* __restrict__ dl_b)
{
    const int tid = threadIdx.x;
    const int d = blockIdx.x * 256 + tid;
    const int c = blockIdx.y;
    const int z = blockIdx.z;
    const int dir = z >> 2, b = z & 3;

    const float* Alog = dir ? Alog_b : Alog_f;
    const float* xdbl = dir ? xdbl_b : xdbl_f;
    const bf16* xc    = dir ? xc_b   : xc_f;
    bf16* dl          = dir ? dl_b   : dl_f;
    const int rowBase = b * LL + c * SCHUNK;

    __shared__ float bs[SCHUNK][32];
#pragma unroll
    for (int i = 0; i < SCHUNK * 32 / 256; ++i) {
        int e = tid + 256 * i;
        int r = e >> 5, n = e & 31;
        bs[r][n] = xdbl[(size_t)(rowBase + r) * 96 + DTRANK + n];
    }
    __syncthreads();

    float Dv = (dir ? Db : Df)[d];
    size_t base = (size_t)z * SNC + c;
    float Aa[DSTATE], h[DSTATE];
#pragma unroll
    for (int n = 0; n < DSTATE; ++n) {
        Aa[n] = -__expf(Alog[d * DSTATE + n]);
        h[n] = hin[(base * DSTATE + n) * DINNER + d];
    }
    const bool fast = a_is_arange(Aa);
    const float a0l2 = Aa[0] * 1.44269504f;

    float nxd = __bfloat162float(dl[(size_t)rowBase * DINNER + d]);
    float nxu = __bfloat162float(xc[(size_t)rowBase * DINNER + d]);

    if (fast) {
#pragma unroll 4
        for (int t = 0; t < SCHUNK; ++t) {
            float delta = nxd, u = nxu;
            if (t + 1 < SCHUNK) {
                size_t nrow = (size_t)(rowBase + t + 1);
                nxd = __bfloat162float(dl[nrow * DINNER + d]);
                nxu = __bfloat162float(xc[nrow * DINNER + d]);
            }
            u = fminf(fmaxf(u, -10.f), 10.f);
            float du = delta * u;
            float p[DSTATE];
            p[0] = exp2f(delta * a0l2);
#pragma unroll
            for (int n = 1; n < DSTATE; ++n)
                p[n] = p[n >> 1] * p[(n - 1) >> 1];
            float y = 0.f;
#pragma unroll
            for (int n = 0; n < DSTATE; ++n) {
                h[n] = p[n] * h[n] + du * bs[t][n];
                y += h[n] * bs[t][DSTATE + n];
            }
            dl[(size_t)(rowBase + t) * DINNER + d] = __float2bfloat16(y + u * Dv);
        }
    } else {
#pragma unroll 4
        for (int t = 0; t < SCHUNK; ++t) {
            float delta = nxd, u = nxu;
            if (t + 1 < SCHUNK) {
                size_t nrow = (size_t)(rowBase + t + 1);
                nxd = __bfloat162float(dl[nrow * DINNER + d]);
                nxu = __bfloat162float(xc[nrow * DINNER + d]);
            }
            u = fminf(fmaxf(u, -10.f), 10.f);
            float du = delta * u;
            float y = 0.f;
#pragma unroll
            for (int n = 0; n < DSTATE; ++n) {
                h[n] = __expf(delta * Aa[n]) * h[n] + du * bs[t][n];
                y += h[n] * bs[t][DSTATE + n];
            }
            dl[(size_t)(rowBase + t) * DINNER + d] = __float2bfloat16(y + u * Dv);
        }
    }
}

// ---------------------------------------------------------------------------
// Gate + out_pw cast fused (bf16 y inputs)
// ---------------------------------------------------------------------------
__global__ __launch_bounds__(256) void gate_cast(
    const bf16* __restrict__ yf, const bf16* __restrict__ yb,
    const float* __restrict__ xz, bf16* __restrict__ ytot,
    const float* __restrict__ out_pw, bf16* __restrict__ obf)
{
    int bid = blockIdx.x;
    if (bid < 16384) {
        int idx = bid * 256 + threadIdx.x;
        int d = idx & (DINNER - 1);
        int l = (idx >> 11) & (LL - 1);
        int b = idx >> 20;
        size_t rowf = (size_t)(b * LL + l);
        size_t rowb = (size_t)(b * LL + (LL - 1 - l));
        float y = __bfloat162float(yf[rowf * DINNER + d]) +
                  __bfloat162float(yb[rowb * DINNER + d]);
        float z = xz[rowf * (2 * DINNER) + DINNER + d];
        float s = z / (1.f + __expf(-z));
        ytot[rowf * DINNER + d] = __float2bfloat16(y * s);
    } else {
        int i = ((bid - 16384) * 256 + threadIdx.x) * 8;
        float4 x = *(const float4*)&out_pw[i];
        float4 y = *(const float4*)&out_pw[i + 4];
        bf16 t[8] = { __float2bfloat16(x.x), __float2bfloat16(x.y),
                      __float2bfloat16(x.z), __float2bfloat16(x.w),
                      __float2bfloat16(y.x), __float2bfloat16(y.y),
                      __float2bfloat16(y.z), __float2bfloat16(y.w) };
        *(short8*)&obf[i] = *(short8*)t;
    }
}

// ---------------------------------------------------------------------------
extern "C" void kernel_launch(void* const* d_in, const int* in_sizes, int n_in,
                              void* d_out, int out_size, void* d_ws, size_t ws_size,
                              hipStream_t stream)
{
    const float* hidden    = (const float*)d_in[0];
    const float* in_proj_w = (const float*)d_in[1];
    const float* conv_w    = (const float*)d_in[2];
    const float* conv_b    = (const float*)d_in[3];
    const float* xproj_w   = (const float*)d_in[4];
    const float* dtproj_w  = (const float*)d_in[5];
    const float* dtproj_b  = (const float*)d_in[6];
    const float* A_log     = (const float*)d_in[7];
    const float* Dvec      = (const float*)d_in[8];
    const float* conv_bw   = (const float*)d_in[9];
    const float* conv_bb   = (const float*)d_in[10];
    const float* xproj_bw  = (const float*)d_in[11];
    const float* dtproj_bw = (const float*)d_in[12];
    const float* dtproj_bb = (const float*)d_in[13];
    const float* A_b_log   = (const float*)d_in[14];
    const float* D_b       = (const float*)d_in[15];
    const float* out_pw    = (const float*)d_in[16];
    float* out = (float*)d_out;

    // Workspace layout (f32 elements). Total 31,916,032 = 127.7 MB.
    // Region names kept from R11; several now hold bf16 data (first half).
    float* ws = (float*)d_ws;
    float* xz      = ws;                       // 8388608
    float* xcR_f   = xz + 8388608;             // 4194304 region: bf16 xc fwd
    float* xcR_b   = xcR_f + 4194304;          // 4194304 region: bf16 xc bwd
    float* xdbl_f  = xcR_b + 4194304;          // 196608
    float* xdbl_b  = xdbl_f + 196608;          // 196608
    float* dlR_f   = xdbl_b + 196608;          // 4194304 region: bf16 delta/y fwd
    float* dlR_b   = dlR_f + 4194304;          // 4194304 region: bf16 delta/y bwd
    float* g2part  = dlR_b + 4194304;          // 1572864
    float* sdel    = g2part + 1572864;         // 262144
    float* hend    = sdel + 262144;            // 4194304; becomes hin in place
    float* smallb  = hend + 4194304;           // 327680

    // bf16 views / aliases (liveness audited R13):
    bf16* xcbf = (bf16*)xcR_f;                 // conv -> g2/scan1/scan2; then dead
    bf16* xcbb = (bf16*)xcR_b;
    bf16* dlbf_f = (bf16*)dlR_f;               // g3 -> scan1/scan2(y) -> gate
    bf16* dlbf_b = (bf16*)dlR_b;
    bf16* hbf = (bf16*)dlR_f;                  // cast_all->G1; overwritten by g3 later
    bf16* wbf = (bf16*)(dlR_f + 1048576);      // cast_all->G1
    bf16* wxf = (bf16*)dlR_b;                  // cast_all->g2; overwritten by g3 later
    bf16* wxb = (bf16*)(dlR_b + 98304);
    bf16* xdbl_bf = (bf16*)smallb;             // g2_reduce->g3
    bf16* dtw_bf  = (bf16*)(smallb + 196608);  // cast_all->g3
    bf16* ytot_bf = (bf16*)xcR_f;              // gate->g4 (xc dead after scan2)
    bf16* obf = (bf16*)xcR_b;                  // gate_cast->g4
    float* g4part = dlR_f;                     // g4 partials (dl dead after gate)

    dim3 blk(256);

    // all pre-G1 casts in one launch
    cast_all<<<dim3(3392), blk, 0, stream>>>(
        hidden, in_proj_w, xproj_w, xproj_bw, dtproj_w, dtproj_bw,
        hbf, wbf, wxf, wxb, dtw_bf, dtw_bf + 131072);

    // G1: xz = hidden @ in_proj_w.T   (M=2048, N=4096, K=1024) bf16 MFMA
    gemm_bf16<0><<<dim3(4096 / 128, MROWS / 128), blk, 0, stream>>>(
        hbf, wbf, xz, 4096, 1024, 1024, 1024, 4096);

    // conv both dirs, 4 channels/thread, bf16 output only
    conv_kernel<<<dim3(2 * BB * LL * DINNER / 4 / 256), blk, 0, stream>>>(
        xz, conv_w, conv_b, conv_bw, conv_bb, xcbf, xcbb);

    // G2 via bf16 MFMA split-K
    g2_mfma<<<dim3(16, G2KS, 2), blk, 0, stream>>>(
        xcbf, xcbb, wxf, wxb, g2part);
    g2_reduce<<<dim3(2 * 2048 * 96 / 256), blk, 0, stream>>>(
        g2part, xdbl_f, xdbl_b, xdbl_bf);

    // G3 via bf16 MFMA (both dirs) -> bf16 delta
    g3_mfma<<<dim3(16, 16, 2), blk, 0, stream>>>(
        xdbl_bf, dtw_bf, dtproj_b, dtproj_bb, dlbf_f, dlbf_b);

    // chunked scan (bf16 delta/u, SCHUNK=32, in-place combine, arange-A fast)
    scan1_kernel<<<dim3(DINNER / 256, SNC, 8), blk, 0, stream>>>(
        A_log, A_b_log, xdbl_f, xdbl_b, xcbf, xcbb, dlbf_f, dlbf_b, sdel, hend);
    scan_combine<<<dim3(2 * BB * DSTATE * DINNER / 256), blk, 0, stream>>>(
        A_log, A_b_log, sdel, hend);
    scan2_kernel<<<dim3(DINNER / 256, SNC, 8), blk, 0, stream>>>(
        A_log, A_b_log, Dvec, D_b, xdbl_f, xdbl_b, xcbf, xcbb, hend, dlbf_f, dlbf_b);

    // gate -> bf16 ytot (overwrites xc region), + out_pw cast (fused)
    gate_cast<<<dim3(16384 + 1024), blk, 0, stream>>>(
        dlbf_f, dlbf_b, xz, ytot_bf, out_pw, obf);

    // G4 split-K=2 + fused reduce/nan_to_num
    g4_mfma<<<dim3(1024 / 128, MROWS / 128, 2), blk, 0, stream>>>(
        ytot_bf, obf, g4part);
    g4_reduce<<<dim3(2048 * 1024 / 4 / 256), blk, 0, stream>>>(g4part, out);
}

// Round 15
// 212.477 us; speedup vs baseline: 1.0586x; 1.0319x over previous
//
#include <hip/hip_runtime.h>
#include <hip/hip_bf16.h>
#include <math.h>

// Problem constants
#define BB 4
#define LL 512
#define DMODEL 1024
#define DSTATE 16
#define DCONV 4
#define DINNER 2048
#define DTRANK 64
#define MROWS (BB*LL)          // 2048 rows of (b,l)
#define G2KS 4                 // split-K factor for the N=96 GEMM
#define SCHUNK 32              // scan chunk length
#define SNC (LL / SCHUNK)      // 16 chunks

typedef __hip_bfloat16 bf16;
typedef __attribute__((ext_vector_type(8))) short short8;
typedef __attribute__((ext_vector_type(4))) short short4v;
typedef __attribute__((ext_vector_type(4))) float f32x4;

__device__ __forceinline__ float softplusf(float x) {
    return x > 20.f ? x : log1pf(__expf(x));
}

// Async global->LDS, 16B per lane (wave-uniform LDS base, per-lane global src)
__device__ __forceinline__ void stage16(const void* g, void* l) {
    __builtin_amdgcn_global_load_lds(
        (const __attribute__((address_space(1))) void*)g,
        (__attribute__((address_space(3))) void*)l, 16, 0, 0);
}

// A has the Vim structure Aa[n] == (n+1)*Aa[0]?
__device__ __forceinline__ bool a_is_arange(const float* Aa) {
    bool ok = true;
#pragma unroll
    for (int n = 1; n < DSTATE; ++n) {
        float k = (float)(n + 1);
        ok = ok && (fabsf(Aa[n] - k * Aa[0]) <= 1e-4f * k * fabsf(Aa[0]));
    }
    return ok;
}

// ---------------------------------------------------------------------------
// G1: bf16 MFMA TN GEMM -> bf16 output. Twin-buffer BK=64 (32 MFMA/barrier).
// ---------------------------------------------------------------------------
__global__ __launch_bounds__(256) void gemm_bf16(
    const bf16* __restrict__ A, const bf16* __restrict__ W,
    bf16* __restrict__ C, int N, int K, int lda, int ldw, int ldc)
{
    __shared__ bf16 lA[2][128 * 32];
    __shared__ bf16 lW[2][128 * 32];

    const int tid = threadIdx.x;
    const int lane = tid & 63;
    const int wid = tid >> 6;
    const int wr = wid >> 1;
    const int wc = wid & 1;
    const int rowBase = blockIdx.y * 128;
    const int colBase = blockIdx.x * 128;

    const int r16 = lane & 15;
    const int kg = lane >> 4;
    const int srow = (lane >> 2);
    const int scol = (lane & 3) * 8;

    f32x4 acc[4][4];
#pragma unroll
    for (int m = 0; m < 4; ++m)
#pragma unroll
        for (int n = 0; n < 4; ++n) acc[m][n] = (f32x4)0.f;

    for (int k0 = 0; k0 < K; k0 += 64) {
#pragma unroll
        for (int h = 0; h < 2; ++h) {
#pragma unroll
            for (int c = 0; c < 2; ++c) {
                int r = wid * 32 + c * 16 + srow;
                stage16(&A[(size_t)(rowBase + r) * lda + k0 + h * 32 + scol],
                        &lA[h][(wid * 32 + c * 16) * 32]);
                stage16(&W[(size_t)(colBase + r) * ldw + k0 + h * 32 + scol],
                        &lW[h][(wid * 32 + c * 16) * 32]);
            }
        }
        __syncthreads();

#pragma unroll
        for (int h = 0; h < 2; ++h) {
            short8 a[4], b[4];
#pragma unroll
            for (int m = 0; m < 4; ++m)
                a[m] = *(const short8*)&lA[h][(wr * 64 + m * 16 + r16) * 32 + kg * 8];
#pragma unroll
            for (int n = 0; n < 4; ++n)
                b[n] = *(const short8*)&lW[h][(wc * 64 + n * 16 + r16) * 32 + kg * 8];
#pragma unroll
            for (int m = 0; m < 4; ++m)
#pragma unroll
                for (int n = 0; n < 4; ++n)
                    acc[m][n] = __builtin_amdgcn_mfma_f32_16x16x32_bf16(
                        a[m], b[n], acc[m][n], 0, 0, 0);
        }
        __syncthreads();
    }

#pragma unroll
    for (int m = 0; m < 4; ++m) {
#pragma unroll
        for (int n = 0; n < 4; ++n) {
            int gc = colBase + wc * 64 + n * 16 + r16;
#pragma unroll
            for (int j = 0; j < 4; ++j) {
                int gr = rowBase + wr * 64 + m * 16 + kg * 4 + j;
                C[(size_t)gr * ldc + gc] = __float2bfloat16(acc[m][n][j]);
            }
        }
    }
}

// ---------------------------------------------------------------------------
// G4 split-K, twin-buffer BK=64, fp32 partials
// ---------------------------------------------------------------------------
__global__ __launch_bounds__(256) void g4_mfma(
    const bf16* __restrict__ A, const bf16* __restrict__ W,
    float* __restrict__ part)   // [2][2048][1024]
{
    const int kz = blockIdx.z;
    const int kOff = kz * 1024;
    float* C = part + (size_t)kz * 2048 * 1024;

    __shared__ bf16 lA[2][128 * 32];
    __shared__ bf16 lW[2][128 * 32];

    const int tid = threadIdx.x;
    const int lane = tid & 63;
    const int wid = tid >> 6;
    const int wr = wid >> 1;
    const int wc = wid & 1;
    const int rowBase = blockIdx.y * 128;
    const int colBase = blockIdx.x * 128;

    const int r16 = lane & 15;
    const int kg = lane >> 4;
    const int srow = (lane >> 2);
    const int scol = (lane & 3) * 8;

    f32x4 acc[4][4];
#pragma unroll
    for (int m = 0; m < 4; ++m)
#pragma unroll
        for (int n = 0; n < 4; ++n) acc[m][n] = (f32x4)0.f;

    for (int k0 = 0; k0 < 1024; k0 += 64) {
#pragma unroll
        for (int h = 0; h < 2; ++h) {
#pragma unroll
            for (int c = 0; c < 2; ++c) {
                int r = wid * 32 + c * 16 + srow;
                stage16(&A[(size_t)(rowBase + r) * 2048 + kOff + k0 + h * 32 + scol],
                        &lA[h][(wid * 32 + c * 16) * 32]);
                stage16(&W[(size_t)(colBase + r) * 2048 + kOff + k0 + h * 32 + scol],
                        &lW[h][(wid * 32 + c * 16) * 32]);
            }
        }
        __syncthreads();

#pragma unroll
        for (int h = 0; h < 2; ++h) {
            short8 a[4], b[4];
#pragma unroll
            for (int m = 0; m < 4; ++m)
                a[m] = *(const short8*)&lA[h][(wr * 64 + m * 16 + r16) * 32 + kg * 8];
#pragma unroll
            for (int n = 0; n < 4; ++n)
                b[n] = *(const short8*)&lW[h][(wc * 64 + n * 16 + r16) * 32 + kg * 8];
#pragma unroll
            for (int m = 0; m < 4; ++m)
#pragma unroll
                for (int n = 0; n < 4; ++n)
                    acc[m][n] = __builtin_amdgcn_mfma_f32_16x16x32_bf16(
                        a[m], b[n], acc[m][n], 0, 0, 0);
        }
        __syncthreads();
    }

#pragma unroll
    for (int m = 0; m < 4; ++m) {
#pragma unroll
        for (int n = 0; n < 4; ++n) {
            int gc = colBase + wc * 64 + n * 16 + r16;
#pragma unroll
            for (int j = 0; j < 4; ++j) {
                int gr = rowBase + wr * 64 + m * 16 + kg * 4 + j;
                C[(size_t)gr * 1024 + gc] = acc[m][n][j];
            }
        }
    }
}

// g4_reduce: out = nan_to_num(p0 + p1)
__global__ __launch_bounds__(256) void g4_reduce(
    const float* __restrict__ part, float* __restrict__ out)
{
    int i = (blockIdx.x * 256 + threadIdx.x) * 4;
    float4 p0 = *(const float4*)&part[i];
    float4 p1 = *(const float4*)&part[2048 * 1024 + i];
    float r[4] = { p0.x + p1.x, p0.y + p1.y, p0.z + p1.z, p0.w + p1.w };
#pragma unroll
    for (int j = 0; j < 4; ++j) {
        float v = r[j];
        if (isnan(v)) v = 0.f;
        else if (isinf(v)) v = (v > 0.f) ? 1.f : -1.f;
        r[j] = v;
    }
    *(float4*)&out[i] = *(float4*)r;
}

// ---------------------------------------------------------------------------
// G3 as bf16 MFMA + dt epilogue -> bf16 delta (single K=64 iteration).
// ---------------------------------------------------------------------------
__global__ __launch_bounds__(256) void g3_mfma(
    const bf16* __restrict__ xdbl_bf,   // [2][2048][96]
    const bf16* __restrict__ dtw_bf,    // [2][2048][64]
    const float* __restrict__ biasf, const float* __restrict__ biasb,
    bf16* __restrict__ of, bf16* __restrict__ ob)
{
    const int dir = blockIdx.z;
    const bf16* A = xdbl_bf + (size_t)dir * 2048 * 96;
    const bf16* W = dtw_bf + (size_t)dir * 2048 * 64;
    const float* bias = dir ? biasb : biasf;
    bf16* C = dir ? ob : of;

    __shared__ bf16 lA[2][128 * 32];
    __shared__ bf16 lW[2][128 * 32];

    const int tid = threadIdx.x;
    const int lane = tid & 63;
    const int wid = tid >> 6;
    const int wr = wid >> 1;
    const int wc = wid & 1;
    const int rowBase = blockIdx.y * 128;
    const int colBase = blockIdx.x * 128;

    const int r16 = lane & 15;
    const int kg = lane >> 4;
    const int srow = (lane >> 2);
    const int scol = (lane & 3) * 8;

    f32x4 acc[4][4];
#pragma unroll
    for (int m = 0; m < 4; ++m)
#pragma unroll
        for (int n = 0; n < 4; ++n) acc[m][n] = (f32x4)0.f;

#pragma unroll
    for (int h = 0; h < 2; ++h) {
#pragma unroll
        for (int c = 0; c < 2; ++c) {
            int r = wid * 32 + c * 16 + srow;
            stage16(&A[(size_t)(rowBase + r) * 96 + h * 32 + scol],
                    &lA[h][(wid * 32 + c * 16) * 32]);
            stage16(&W[(size_t)(colBase + r) * 64 + h * 32 + scol],
                    &lW[h][(wid * 32 + c * 16) * 32]);
        }
    }
    __syncthreads();

#pragma unroll
    for (int h = 0; h < 2; ++h) {
        short8 a[4], b[4];
#pragma unroll
        for (int m = 0; m < 4; ++m)
            a[m] = *(const short8*)&lA[h][(wr * 64 + m * 16 + r16) * 32 + kg * 8];
#pragma unroll
        for (int n = 0; n < 4; ++n)
            b[n] = *(const short8*)&lW[h][(wc * 64 + n * 16 + r16) * 32 + kg * 8];
#pragma unroll
        for (int m = 0; m < 4; ++m)
#pragma unroll
            for (int n = 0; n < 4; ++n)
                acc[m][n] = __builtin_amdgcn_mfma_f32_16x16x32_bf16(
                    a[m], b[n], acc[m][n], 0, 0, 0);
    }

#pragma unroll
    for (int m = 0; m < 4; ++m) {
#pragma unroll
        for (int n = 0; n < 4; ++n) {
            int gc = colBase + wc * 64 + n * 16 + r16;
            float bv = bias[gc];
#pragma unroll
            for (int j = 0; j < 4; ++j) {
                int gr = rowBase + wr * 64 + m * 16 + kg * 4 + j;
                float t = acc[m][n][j] + bv;
                t = fminf(fmaxf(t, 1e-5f), 1.0f);
                C[(size_t)gr * 2048 + gc] = __float2bfloat16(softplusf(t + bv));
            }
        }
    }
}

// ---------------------------------------------------------------------------
// G2 as bf16 MFMA split-K (reg-staged)
// ---------------------------------------------------------------------------
__global__ __launch_bounds__(256) void g2_mfma(
    const bf16* __restrict__ xcbf_f, const bf16* __restrict__ xcbf_b,
    const bf16* __restrict__ wxf, const bf16* __restrict__ wxb,
    float* __restrict__ part)   // [2][G2KS][2048][96]
{
    const int dir = blockIdx.z;
    const bf16* A = dir ? xcbf_b : xcbf_f;
    const bf16* W = dir ? wxb : wxf;
    const int rowBase = blockIdx.x * 128;
    const int kz = blockIdx.y;
    const int kBase = kz * (2048 / G2KS);

    __shared__ bf16 lA[128 * 40];
    __shared__ bf16 lW[96 * 40];

    const int tid = threadIdx.x;
    const int lane = tid & 63;
    const int wid = tid >> 6;
    const int r16 = lane & 15;
    const int kg = lane >> 4;

    f32x4 acc[2][6];
#pragma unroll
    for (int m = 0; m < 2; ++m)
#pragma unroll
        for (int n = 0; n < 6; ++n) acc[m][n] = (f32x4)0.f;

    const int srow = tid >> 2;
    const int scol = (tid & 3) * 8;

    for (int k0 = 0; k0 < 2048 / G2KS; k0 += 32) {
#pragma unroll
        for (int it = 0; it < 2; ++it) {
            int r = srow + it * 64;
            short8 va = *(const short8*)&A[(size_t)(rowBase + r) * 2048 + kBase + k0 + scol];
            *(short8*)&lA[r * 40 + scol] = va;
        }
        {
            short8 vw = *(const short8*)&W[(size_t)srow * 2048 + kBase + k0 + scol];
            *(short8*)&lW[srow * 40 + scol] = vw;
        }
        if (tid < 128) {
            int r = 64 + (tid >> 2);
            short8 vw2 = *(const short8*)&W[(size_t)r * 2048 + kBase + k0 + scol];
            *(short8*)&lW[r * 40 + scol] = vw2;
        }
        __syncthreads();

        short8 a[2], b[6];
#pragma unroll
        for (int m = 0; m < 2; ++m)
            a[m] = *(const short8*)&lA[(wid * 32 + m * 16 + r16) * 40 + kg * 8];
#pragma unroll
        for (int n = 0; n < 6; ++n)
            b[n] = *(const short8*)&lW[(n * 16 + r16) * 40 + kg * 8];
#pragma unroll
        for (int m = 0; m < 2; ++m)
#pragma unroll
            for (int n = 0; n < 6; ++n)
                acc[m][n] = __builtin_amdgcn_mfma_f32_16x16x32_bf16(
                    a[m], b[n], acc[m][n], 0, 0, 0);
        __syncthreads();
    }

    float* p = part + ((size_t)(dir * G2KS + kz) * 2048) * 96;
#pragma unroll
    for (int m = 0; m < 2; ++m) {
#pragma unroll
        for (int n = 0; n < 6; ++n) {
            int gc = n * 16 + r16;
#pragma unroll
            for (int j = 0; j < 4; ++j) {
                int gr = rowBase + wid * 32 + m * 16 + kg * 4 + j;
                p[(size_t)gr * 96 + gc] = acc[m][n][j];
            }
        }
    }
}

// g2_reduce: sum split-K partials -> fp32 xdbl AND bf16 xdbl copy (for g3)
__global__ __launch_bounds__(256) void g2_reduce(
    const float* __restrict__ part, float* __restrict__ xf, float* __restrict__ xb,
    bf16* __restrict__ xdbl_bf)
{
    int idx = blockIdx.x * 256 + threadIdx.x;
    int c = idx % 96;
    int r = (idx / 96) & 2047;
    int dir = idx / (96 * 2048);
    float s = 0.f;
#pragma unroll
    for (int ks = 0; ks < G2KS; ++ks)
        s += part[((size_t)(dir * G2KS + ks) * 2048 + r) * 96 + c];
    (dir ? xb : xf)[(size_t)r * 96 + c] = s;
    xdbl_bf[((size_t)dir * 2048 + r) * 96 + c] = __float2bfloat16(s);
}

// ---------------------------------------------------------------------------
// Fused f32 -> bf16 casts (all pre-G1 casts, one launch)
// ---------------------------------------------------------------------------
__global__ __launch_bounds__(256) void cast_all(
    const float* __restrict__ hidden, const float* __restrict__ in_proj_w,
    const float* __restrict__ xproj_w, const float* __restrict__ xproj_bw,
    const float* __restrict__ dtproj_w, const float* __restrict__ dtproj_bw,
    bf16* __restrict__ hbf, bf16* __restrict__ wbf,
    bf16* __restrict__ wxf, bf16* __restrict__ wxb,
    bf16* __restrict__ dtwf, bf16* __restrict__ dtwb)
{
    int bid = blockIdx.x;
    const float* src; bf16* dst; int base;
    if (bid < 1024)      { src = hidden;    dst = hbf;  base = bid; }
    else if (bid < 3072) { src = in_proj_w; dst = wbf;  base = bid - 1024; }
    else if (bid < 3168) { src = xproj_w;   dst = wxf;  base = bid - 3072; }
    else if (bid < 3264) { src = xproj_bw;  dst = wxb;  base = bid - 3168; }
    else if (bid < 3328) { src = dtproj_w;  dst = dtwf; base = bid - 3264; }
    else                 { src = dtproj_bw; dst = dtwb; base = bid - 3328; }
    int i = (base * 256 + threadIdx.x) * 8;
    float4 x = *(const float4*)&src[i];
    float4 y = *(const float4*)&src[i + 4];
    bf16 t[8] = { __float2bfloat16(x.x), __float2bfloat16(x.y),
                  __float2bfloat16(x.z), __float2bfloat16(x.w),
                  __float2bfloat16(y.x), __float2bfloat16(y.y),
                  __float2bfloat16(y.z), __float2bfloat16(y.w) };
    *(short8*)&dst[i] = *(short8*)t;
}

// ---------------------------------------------------------------------------
// Depthwise causal conv1d, 4 channels/thread. bf16 xz input, bf16 xc output.
// ---------------------------------------------------------------------------
__global__ __launch_bounds__(256) void conv_kernel(
    const bf16* __restrict__ xz,
    const float* __restrict__ wf, const float* __restrict__ bf,
    const float* __restrict__ wb, const float* __restrict__ bb,
    bf16* __restrict__ xcbf, bf16* __restrict__ xcbb)
{
    int idx = blockIdx.x * 256 + threadIdx.x;
    int dg = idx & 511;
    int rest = idx >> 9;
    int l = rest & (LL - 1);
    int b = (rest >> 9) & (BB - 1);
    int dir = rest >> 11;
    int d0 = dg * 4;

    const float* w = dir ? wb : wf;
    const float* bias = dir ? bb : bf;

    float4 wv[4];
#pragma unroll
    for (int c = 0; c < 4; ++c)
        wv[c] = *(const float4*)&w[(d0 + c) * DCONV];

    float4 acc = *(const float4*)&bias[d0];
#pragma unroll
    for (int k = 0; k < DCONV; ++k) {
        int j = l - (DCONV - 1) + k;
        if (j >= 0) {
            int jj = dir ? (LL - 1 - j) : j;
            short4v xv = *(const short4v*)&xz[((size_t)(b * LL + jj)) * (2 * DINNER) + d0];
            const bf16* xp = (const bf16*)&xv;
            acc.x += ((const float*)&wv[0])[k] * __bfloat162float(xp[0]);
            acc.y += ((const float*)&wv[1])[k] * __bfloat162float(xp[1]);
            acc.z += ((const float*)&wv[2])[k] * __bfloat162float(xp[2]);
            acc.w += ((const float*)&wv[3])[k] * __bfloat162float(xp[3]);
        }
    }

    size_t off = ((size_t)(b * LL + l)) * DINNER + d0;
    bf16 t[4] = { __float2bfloat16(acc.x), __float2bfloat16(acc.y),
                  __float2bfloat16(acc.z), __float2bfloat16(acc.w) };
    *(short4v*)&((dir ? xcbb : xcbf)[off]) = *(short4v*)t;
}

// ---------------------------------------------------------------------------
// Chunked scan phase 1 (bf16 delta/u inputs, arange-A fast path)
// ---------------------------------------------------------------------------
__global__ __launch_bounds__(256) void scan1_kernel(
    const float* __restrict__ Alog_f, const float* __restrict__ Alog_b,
    const float* __restrict__ xdbl_f, const float* __restrict__ xdbl_b,
    const bf16* __restrict__ xc_f, const bf16* __restrict__ xc_b,
    const bf16* __restrict__ dl_f, const bf16* __restrict__ dl_b,
    float* __restrict__ sdel, float* __restrict__ hend)
{
    const int tid = threadIdx.x;
    const int d = blockIdx.x * 256 + tid;
    const int c = blockIdx.y;
    const int z = blockIdx.z;           // dir*4 + b
    const int dir = z >> 2, b = z & 3;

    const float* Alog = dir ? Alog_b : Alog_f;
    const float* xdbl = dir ? xdbl_b : xdbl_f;
    const bf16* xc    = dir ? xc_b   : xc_f;
    const bf16* dl    = dir ? dl_b   : dl_f;
    const int rowBase = b * LL + c * SCHUNK;

    __shared__ float bs[SCHUNK][16];
#pragma unroll
    for (int i = 0; i < SCHUNK * 16 / 256; ++i) {
        int e = tid + 256 * i;
        int r = e >> 4, n = e & 15;
        bs[r][n] = xdbl[(size_t)(rowBase + r) * 96 + DTRANK + n];
    }
    __syncthreads();

    float Aa[DSTATE], h[DSTATE];
#pragma unroll
    for (int n = 0; n < DSTATE; ++n) {
        Aa[n] = -__expf(Alog[d * DSTATE + n]);
        h[n] = 0.f;
    }
    float sd = 0.f;
    const bool fast = a_is_arange(Aa);
    const float a0l2 = Aa[0] * 1.44269504f;

    float nxd = __bfloat162float(dl[(size_t)rowBase * DINNER + d]);
    float nxu = __bfloat162float(xc[(size_t)rowBase * DINNER + d]);

    if (fast) {
#pragma unroll 4
        for (int t = 0; t < SCHUNK; ++t) {
            float delta = nxd, u = nxu;
            if (t + 1 < SCHUNK) {
                size_t nrow = (size_t)(rowBase + t + 1);
                nxd = __bfloat162float(dl[nrow * DINNER + d]);
                nxu = __bfloat162float(xc[nrow * DINNER + d]);
            }
            u = fminf(fmaxf(u, -10.f), 10.f);
            float du = delta * u;
            sd += delta;
            float p[DSTATE];
            p[0] = exp2f(delta * a0l2);
#pragma unroll
            for (int n = 1; n < DSTATE; ++n)
                p[n] = p[n >> 1] * p[(n - 1) >> 1];
#pragma unroll
            for (int n = 0; n < DSTATE; ++n)
                h[n] = p[n] * h[n] + du * bs[t][n];
        }
    } else {
#pragma unroll 4
        for (int t = 0; t < SCHUNK; ++t) {
            float delta = nxd, u = nxu;
            if (t + 1 < SCHUNK) {
                size_t nrow = (size_t)(rowBase + t + 1);
                nxd = __bfloat162float(dl[nrow * DINNER + d]);
                nxu = __bfloat162float(xc[nrow * DINNER + d]);
            }
            u = fminf(fmaxf(u, -10.f), 10.f);
            float du = delta * u;
            sd += delta;
#pragma unroll
            for (int n = 0; n < DSTATE; ++n)
                h[n] = __expf(delta * Aa[n]) * h[n] + du * bs[t][n];
        }
    }

    size_t base = (size_t)z * SNC + c;
    sdel[base * DINNER + d] = sd;
#pragma unroll
    for (int n = 0; n < DSTATE; ++n)
        hend[(base * DSTATE + n) * DINNER + d] = h[n];
}

// ---------------------------------------------------------------------------
// Combine (n-parallel, IN PLACE)
// ---------------------------------------------------------------------------
__global__ __launch_bounds__(256) void scan_combine(
    const float* __restrict__ Alog_f, const float* __restrict__ Alog_b,
    const float* __restrict__ sdel, float* __restrict__ hend)
{
    int g = blockIdx.x * 256 + threadIdx.x;
    int d = g & (DINNER - 1);
    int n = (g >> 11) & (DSTATE - 1);
    int z = g >> 15;
    const float* Alog = (z >> 2) ? Alog_b : Alog_f;

    float Aa = -__expf(Alog[d * DSTATE + n]);
    float hr = 0.f;
    for (int c = 0; c < SNC; ++c) {
        size_t base = (size_t)z * SNC + c;
        size_t idx = (base * DSTATE + n) * DINNER + d;
        float he = hend[idx];
        hend[idx] = hr;
        float sd = sdel[base * DINNER + d];
        hr = __expf(sd * Aa) * hr + he;
    }
}

// ---------------------------------------------------------------------------
// Chunked scan phase 2 (bf16 in, bf16 y out in place, arange-A fast path)
// ---------------------------------------------------------------------------
__global__ __launch_bounds__(256) void scan2_kernel(
    const float* __restrict__ Alog_f, const float* __restrict__ Alog_b,
    const float* __restrict__ Df, const float* __restrict__ Db,
    const float* __restrict__ xdbl_f, const float* __restrict__ xdbl_b,
    const bf16* __restrict__ xc_f, const bf16* __restrict__ xc_b,
    const float* __restrict__ hin,
    bf16* __restrict__ dl_f, bf16* __restrict__ dl_b)
{
    const int tid = threadIdx.x;
    const int d = blockIdx.x * 256 + tid;
    const int c = blockIdx.y;
    const int z = blockIdx.z;
    const int dir = z >> 2, b = z & 3;

    const float* Alog = dir ? Alog_b : Alog_f;
    const float* xdbl = dir ? xdbl_b : xdbl_f;
    const bf16* xc    = dir ? xc_b   : xc_f;
    bf16* dl          = dir ? dl_b   : dl_f;
    const int rowBase = b * LL + c * SCHUNK;

    __shared__ float bs[SCHUNK][32];
#pragma unroll
    for (int i = 0; i < SCHUNK * 32 / 256; ++i) {
        int e = tid + 256 * i;
        int r = e >> 5, n = e & 31;
        bs[r][n] = xdbl[(size_t)(rowBase + r) * 96 + DTRANK + n];
    }
    __syncthreads();

    float Dv = (dir ? Db : Df)[d];
    size_t base = (size_t)z * SNC + c;
    float Aa[DSTATE], h[DSTATE];
#pragma unroll
    for (int n = 0; n < DSTATE; ++n) {
        Aa[n] = -__expf(Alog[d * DSTATE + n]);
        h[n] = hin[(base * DSTATE + n) * DINNER + d];
    }
    const bool fast = a_is_arange(Aa);
    const float a0l2 = Aa[0] * 1.44269504f;

    float nxd = __bfloat162float(dl[(size_t)rowBase * DINNER + d]);
    float nxu = __bfloat162float(xc[(size_t)rowBase * DINNER + d]);

    if (fast) {
#pragma unroll 4
        for (int t = 0; t < SCHUNK; ++t) {
            float delta = nxd, u = nxu;
            if (t + 1 < SCHUNK) {
                size_t nrow = (size_t)(rowBase + t + 1);
                nxd = __bfloat162float(dl[nrow * DINNER + d]);
                nxu = __bfloat162float(xc[nrow * DINNER + d]);
            }
            u = fminf(fmaxf(u, -10.f), 10.f);
            float du = delta * u;
            float p[DSTATE];
            p[0] = exp2f(delta * a0l2);
#pragma unroll
            for (int n = 1; n < DSTATE; ++n)
                p[n] = p[n >> 1] * p[(n - 1) >> 1];
            float y = 0.f;
#pragma unroll
            for (int n = 0; n < DSTATE; ++n) {
                h[n] = p[n] * h[n] + du * bs[t][n];
                y += h[n] * bs[t][DSTATE + n];
            }
            dl[(size_t)(rowBase + t) * DINNER + d] = __float2bfloat16(y + u * Dv);
        }
    } else {
#pragma unroll 4
        for (int t = 0; t < SCHUNK; ++t) {
            float delta = nxd, u = nxu;
            if (t + 1 < SCHUNK) {
                size_t nrow = (size_t)(rowBase + t + 1);
                nxd = __bfloat162float(dl[nrow * DINNER + d]);
                nxu = __bfloat162float(xc[nrow * DINNER + d]);
            }
            u = fminf(fmaxf(u, -10.f), 10.f);
            float du = delta * u;
            float y = 0.f;
#pragma unroll
            for (int n = 0; n < DSTATE; ++n) {
                h[n] = __expf(delta * Aa[n]) * h[n] + du * bs[t][n];
                y += h[n] * bs[t][DSTATE + n];
            }
            dl[(size_t)(rowBase + t) * DINNER + d] = __float2bfloat16(y + u * Dv);
        }
    }
}

// ---------------------------------------------------------------------------
// Gate + out_pw cast fused (bf16 y and z inputs)
// ---------------------------------------------------------------------------
__global__ __launch_bounds__(256) void gate_cast(
    const bf16* __restrict__ yf, const bf16* __restrict__ yb,
    const bf16* __restrict__ xz, bf16* __restrict__ ytot,
    const float* __restrict__ out_pw, bf16* __restrict__ obf)
{
    int bid = blockIdx.x;
    if (bid < 16384) {
        int idx = bid * 256 + threadIdx.x;
        int d = idx & (DINNER - 1);
        int l = (idx >> 11) & (LL - 1);
        int b = idx >> 20;
        size_t rowf = (size_t)(b * LL + l);
        size_t rowb = (size_t)(b * LL + (LL - 1 - l));
        float y = __bfloat162float(yf[rowf * DINNER + d]) +
                  __bfloat162float(yb[rowb * DINNER + d]);
        float z = __bfloat162float(xz[rowf * (2 * DINNER) + DINNER + d]);
        float s = z / (1.f + __expf(-z));
        ytot[rowf * DINNER + d] = __float2bfloat16(y * s);
    } else {
        int i = ((bid - 16384) * 256 + threadIdx.x) * 8;
        float4 x = *(const float4*)&out_pw[i];
        float4 y = *(const float4*)&out_pw[i + 4];
        bf16 t[8] = { __float2bfloat16(x.x), __float2bfloat16(x.y),
                      __float2bfloat16(x.z), __float2bfloat16(x.w),
                      __float2bfloat16(y.x), __float2bfloat16(y.y),
                      __float2bfloat16(y.z), __float2bfloat16(y.w) };
        *(short8*)&obf[i] = *(short8*)t;
    }
}

// ---------------------------------------------------------------------------
extern "C" void kernel_launch(void* const* d_in, const int* in_sizes, int n_in,
                              void* d_out, int out_size, void* d_ws, size_t ws_size,
                              hipStream_t stream)
{
    const float* hidden    = (const float*)d_in[0];
    const float* in_proj_w = (const float*)d_in[1];
    const float* conv_w    = (const float*)d_in[2];
    const float* conv_b    = (const float*)d_in[3];
    const float* xproj_w   = (const float*)d_in[4];
    const float* dtproj_w  = (const float*)d_in[5];
    const float* dtproj_b  = (const float*)d_in[6];
    const float* A_log     = (const float*)d_in[7];
    const float* Dvec      = (const float*)d_in[8];
    const float* conv_bw   = (const float*)d_in[9];
    const float* conv_bb   = (const float*)d_in[10];
    const float* xproj_bw  = (const float*)d_in[11];
    const float* dtproj_bw = (const float*)d_in[12];
    const float* dtproj_bb = (const float*)d_in[13];
    const float* A_b_log   = (const float*)d_in[14];
    const float* D_b       = (const float*)d_in[15];
    const float* out_pw    = (const float*)d_in[16];
    float* out = (float*)d_out;

    // Workspace layout (f32 elements). Total 31,916,032 = 127.7 MB.
    float* ws = (float*)d_ws;
    float* xzR     = ws;                       // 8388608 region: bf16 xz (uses first half)
    float* xcR_f   = xzR + 8388608;            // 4194304 region: bf16 xc fwd
    float* xcR_b   = xcR_f + 4194304;          // 4194304 region: bf16 xc bwd
    float* xdbl_f  = xcR_b + 4194304;          // 196608
    float* xdbl_b  = xdbl_f + 196608;          // 196608
    float* dlR_f   = xdbl_b + 196608;          // 4194304 region: bf16 delta/y fwd
    float* dlR_b   = dlR_f + 4194304;          // 4194304 region: bf16 delta/y bwd
    float* g2part  = dlR_b + 4194304;          // 1572864
    float* sdel    = g2part + 1572864;         // 262144
    float* hend    = sdel + 262144;            // 4194304; becomes hin in place
    float* smallb  = hend + 4194304;           // 327680

    // bf16 views / aliases (liveness audited R13/R14):
    bf16* xzbf = (bf16*)xzR;                   // G1 -> conv (x half) + gate (z half)
    bf16* xcbf = (bf16*)xcR_f;                 // conv -> g2/scan1/scan2; then dead
    bf16* xcbb = (bf16*)xcR_b;
    bf16* dlbf_f = (bf16*)dlR_f;               // g3 -> scan1/scan2(y) -> gate
    bf16* dlbf_b = (bf16*)dlR_b;
    bf16* hbf = (bf16*)dlR_f;                  // cast_all->G1; overwritten by g3 later
    bf16* wbf = (bf16*)(dlR_f + 1048576);      // cast_all->G1
    bf16* wxf = (bf16*)dlR_b;                  // cast_all->g2; overwritten by g3 later
    bf16* wxb = (bf16*)(dlR_b + 98304);
    bf16* xdbl_bf = (bf16*)smallb;             // g2_reduce->g3
    bf16* dtw_bf  = (bf16*)(smallb + 196608);  // cast_all->g3
    bf16* ytot_bf = (bf16*)xcR_f;              // gate->g4 (xc dead after scan2)
    bf16* obf = (bf16*)xcR_b;                  // gate_cast->g4
    float* g4part = dlR_f;                     // g4 partials (dl dead after gate)

    dim3 blk(256);

    // all pre-G1 casts in one launch
    cast_all<<<dim3(3392), blk, 0, stream>>>(
        hidden, in_proj_w, xproj_w, xproj_bw, dtproj_w, dtproj_bw,
        hbf, wbf, wxf, wxb, dtw_bf, dtw_bf + 131072);

    // G1: xz = hidden @ in_proj_w.T  (bf16 output, twin-buffer BK=64)
    gemm_bf16<<<dim3(4096 / 128, MROWS / 128), blk, 0, stream>>>(
        hbf, wbf, xzbf, 4096, 1024, 1024, 1024, 4096);

    // conv both dirs (bf16 in/out), 4 channels/thread
    conv_kernel<<<dim3(2 * BB * LL * DINNER / 4 / 256), blk, 0, stream>>>(
        xzbf, conv_w, conv_b, conv_bw, conv_bb, xcbf, xcbb);

    // G2 via bf16 MFMA split-K
    g2_mfma<<<dim3(16, G2KS, 2), blk, 0, stream>>>(
        xcbf, xcbb, wxf, wxb, g2part);
    g2_reduce<<<dim3(2 * 2048 * 96 / 256), blk, 0, stream>>>(
        g2part, xdbl_f, xdbl_b, xdbl_bf);

    // G3 via bf16 MFMA (both dirs) -> bf16 delta
    g3_mfma<<<dim3(16, 16, 2), blk, 0, stream>>>(
        xdbl_bf, dtw_bf, dtproj_b, dtproj_bb, dlbf_f, dlbf_b);

    // chunked scan (bf16 delta/u, SCHUNK=32, in-place combine, arange-A fast)
    scan1_kernel<<<dim3(DINNER / 256, SNC, 8), blk, 0, stream>>>(
        A_log, A_b_log, xdbl_f, xdbl_b, xcbf, xcbb, dlbf_f, dlbf_b, sdel, hend);
    scan_combine<<<dim3(2 * BB * DSTATE * DINNER / 256), blk, 0, stream>>>(
        A_log, A_b_log, sdel, hend);
    scan2_kernel<<<dim3(DINNER / 256, SNC, 8), blk, 0, stream>>>(
        A_log, A_b_log, Dvec, D_b, xdbl_f, xdbl_b, xcbf, xcbb, hend, dlbf_f, dlbf_b);

    // gate -> bf16 ytot (overwrites xc region), + out_pw cast (fused)
    gate_cast<<<dim3(16384 + 1024), blk, 0, stream>>>(
        dlbf_f, dlbf_b, xzbf, ytot_bf, out_pw, obf);

    // G4 split-K=2 (twin-buffer BK=64) + fused reduce/nan_to_num
    g4_mfma<<<dim3(1024 / 128, MROWS / 128, 2), blk, 0, stream>>>(
        ytot_bf, obf, g4part);
    g4_reduce<<<dim3(2048 * 1024 / 4 / 256), blk, 0, stream>>>(g4part, out);
}

// Round 16
// 211.989 us; speedup vs baseline: 1.0610x; 1.0023x over previous
//
#include <hip/hip_runtime.h>
#include <hip/hip_bf16.h>
#include <math.h>

// Problem constants
#define BB 4
#define LL 512
#define DMODEL 1024
#define DSTATE 16
#define DCONV 4
#define DINNER 2048
#define DTRANK 64
#define MROWS (BB*LL)          // 2048 rows of (b,l)
#define G2KS 4                 // split-K factor for the N=96 GEMM
#define SCHUNK 32              // scan chunk length
#define SNC (LL / SCHUNK)      // 16 chunks

typedef __hip_bfloat16 bf16;
typedef __attribute__((ext_vector_type(8))) short short8;
typedef __attribute__((ext_vector_type(4))) short short4v;
typedef __attribute__((ext_vector_type(4))) float f32x4;

__device__ __forceinline__ float softplusf(float x) {
    return x > 20.f ? x : log1pf(__expf(x));
}

// Async global->LDS, 16B per lane (wave-uniform LDS base, per-lane global src)
__device__ __forceinline__ void stage16(const void* g, void* l) {
    __builtin_amdgcn_global_load_lds(
        (const __attribute__((address_space(1))) void*)g,
        (__attribute__((address_space(3))) void*)l, 16, 0, 0);
}

// A has the Vim structure Aa[n] == (n+1)*Aa[0]?
__device__ __forceinline__ bool a_is_arange(const float* Aa) {
    bool ok = true;
#pragma unroll
    for (int n = 1; n < DSTATE; ++n) {
        float k = (float)(n + 1);
        ok = ok && (fabsf(Aa[n] - k * Aa[0]) <= 1e-4f * k * fabsf(Aa[0]));
    }
    return ok;
}

// ---------------------------------------------------------------------------
// G1: bf16 MFMA TN GEMM -> bf16 output. Twin-buffer BK=64 (32 MFMA/barrier).
// ---------------------------------------------------------------------------
__global__ __launch_bounds__(256) void gemm_bf16(
    const bf16* __restrict__ A, const bf16* __restrict__ W,
    bf16* __restrict__ C, int N, int K, int lda, int ldw, int ldc)
{
    __shared__ bf16 lA[2][128 * 32];
    __shared__ bf16 lW[2][128 * 32];

    const int tid = threadIdx.x;
    const int lane = tid & 63;
    const int wid = tid >> 6;
    const int wr = wid >> 1;
    const int wc = wid & 1;
    const int rowBase = blockIdx.y * 128;
    const int colBase = blockIdx.x * 128;

    const int r16 = lane & 15;
    const int kg = lane >> 4;
    const int srow = (lane >> 2);
    const int scol = (lane & 3) * 8;

    f32x4 acc[4][4];
#pragma unroll
    for (int m = 0; m < 4; ++m)
#pragma unroll
        for (int n = 0; n < 4; ++n) acc[m][n] = (f32x4)0.f;

    for (int k0 = 0; k0 < K; k0 += 64) {
#pragma unroll
        for (int h = 0; h < 2; ++h) {
#pragma unroll
            for (int c = 0; c < 2; ++c) {
                int r = wid * 32 + c * 16 + srow;
                stage16(&A[(size_t)(rowBase + r) * lda + k0 + h * 32 + scol],
                        &lA[h][(wid * 32 + c * 16) * 32]);
                stage16(&W[(size_t)(colBase + r) * ldw + k0 + h * 32 + scol],
                        &lW[h][(wid * 32 + c * 16) * 32]);
            }
        }
        __syncthreads();

#pragma unroll
        for (int h = 0; h < 2; ++h) {
            short8 a[4], b[4];
#pragma unroll
            for (int m = 0; m < 4; ++m)
                a[m] = *(const short8*)&lA[h][(wr * 64 + m * 16 + r16) * 32 + kg * 8];
#pragma unroll
            for (int n = 0; n < 4; ++n)
                b[n] = *(const short8*)&lW[h][(wc * 64 + n * 16 + r16) * 32 + kg * 8];
#pragma unroll
            for (int m = 0; m < 4; ++m)
#pragma unroll
                for (int n = 0; n < 4; ++n)
                    acc[m][n] = __builtin_amdgcn_mfma_f32_16x16x32_bf16(
                        a[m], b[n], acc[m][n], 0, 0, 0);
        }
        __syncthreads();
    }

#pragma unroll
    for (int m = 0; m < 4; ++m) {
#pragma unroll
        for (int n = 0; n < 4; ++n) {
            int gc = colBase + wc * 64 + n * 16 + r16;
#pragma unroll
            for (int j = 0; j < 4; ++j) {
                int gr = rowBase + wr * 64 + m * 16 + kg * 4 + j;
                C[(size_t)gr * ldc + gc] = __float2bfloat16(acc[m][n][j]);
            }
        }
    }
}

// ---------------------------------------------------------------------------
// G4 split-K, twin-buffer BK=64, fp32 partials
// ---------------------------------------------------------------------------
__global__ __launch_bounds__(256) void g4_mfma(
    const bf16* __restrict__ A, const bf16* __restrict__ W,
    float* __restrict__ part)   // [2][2048][1024]
{
    const int kz = blockIdx.z;
    const int kOff = kz * 1024;
    float* C = part + (size_t)kz * 2048 * 1024;

    __shared__ bf16 lA[2][128 * 32];
    __shared__ bf16 lW[2][128 * 32];

    const int tid = threadIdx.x;
    const int lane = tid & 63;
    const int wid = tid >> 6;
    const int wr = wid >> 1;
    const int wc = wid & 1;
    const int rowBase = blockIdx.y * 128;
    const int colBase = blockIdx.x * 128;

    const int r16 = lane & 15;
    const int kg = lane >> 4;
    const int srow = (lane >> 2);
    const int scol = (lane & 3) * 8;

    f32x4 acc[4][4];
#pragma unroll
    for (int m = 0; m < 4; ++m)
#pragma unroll
        for (int n = 0; n < 4; ++n) acc[m][n] = (f32x4)0.f;

    for (int k0 = 0; k0 < 1024; k0 += 64) {
#pragma unroll
        for (int h = 0; h < 2; ++h) {
#pragma unroll
            for (int c = 0; c < 2; ++c) {
                int r = wid * 32 + c * 16 + srow;
                stage16(&A[(size_t)(rowBase + r) * 2048 + kOff + k0 + h * 32 + scol],
                        &lA[h][(wid * 32 + c * 16) * 32]);
                stage16(&W[(size_t)(colBase + r) * 2048 + kOff + k0 + h * 32 + scol],
                        &lW[h][(wid * 32 + c * 16) * 32]);
            }
        }
        __syncthreads();

#pragma unroll
        for (int h = 0; h < 2; ++h) {
            short8 a[4], b[4];
#pragma unroll
            for (int m = 0; m < 4; ++m)
                a[m] = *(const short8*)&lA[h][(wr * 64 + m * 16 + r16) * 32 + kg * 8];
#pragma unroll
            for (int n = 0; n < 4; ++n)
                b[n] = *(const short8*)&lW[h][(wc * 64 + n * 16 + r16) * 32 + kg * 8];
#pragma unroll
            for (int m = 0; m < 4; ++m)
#pragma unroll
                for (int n = 0; n < 4; ++n)
                    acc[m][n] = __builtin_amdgcn_mfma_f32_16x16x32_bf16(
                        a[m], b[n], acc[m][n], 0, 0, 0);
        }
        __syncthreads();
    }

#pragma unroll
    for (int m = 0; m < 4; ++m) {
#pragma unroll
        for (int n = 0; n < 4; ++n) {
            int gc = colBase + wc * 64 + n * 16 + r16;
#pragma unroll
            for (int j = 0; j < 4; ++j) {
                int gr = rowBase + wr * 64 + m * 16 + kg * 4 + j;
                C[(size_t)gr * 1024 + gc] = acc[m][n][j];
            }
        }
    }
}

// g4_reduce: out = nan_to_num(p0 + p1)
__global__ __launch_bounds__(256) void g4_reduce(
    const float* __restrict__ part, float* __restrict__ out)
{
    int i = (blockIdx.x * 256 + threadIdx.x) * 4;
    float4 p0 = *(const float4*)&part[i];
    float4 p1 = *(const float4*)&part[2048 * 1024 + i];
    float r[4] = { p0.x + p1.x, p0.y + p1.y, p0.z + p1.z, p0.w + p1.w };
#pragma unroll
    for (int j = 0; j < 4; ++j) {
        float v = r[j];
        if (isnan(v)) v = 0.f;
        else if (isinf(v)) v = (v > 0.f) ? 1.f : -1.f;
        r[j] = v;
    }
    *(float4*)&out[i] = *(float4*)r;
}

// ---------------------------------------------------------------------------
// G3 as bf16 MFMA + dt epilogue -> bf16 delta (single K=64 iteration).
// ---------------------------------------------------------------------------
__global__ __launch_bounds__(256) void g3_mfma(
    const bf16* __restrict__ xdbl_bf,   // [2][2048][96]
    const bf16* __restrict__ dtw_bf,    // [2][2048][64]
    const float* __restrict__ biasf, const float* __restrict__ biasb,
    bf16* __restrict__ of, bf16* __restrict__ ob)
{
    const int dir = blockIdx.z;
    const bf16* A = xdbl_bf + (size_t)dir * 2048 * 96;
    const bf16* W = dtw_bf + (size_t)dir * 2048 * 64;
    const float* bias = dir ? biasb : biasf;
    bf16* C = dir ? ob : of;

    __shared__ bf16 lA[2][128 * 32];
    __shared__ bf16 lW[2][128 * 32];

    const int tid = threadIdx.x;
    const int lane = tid & 63;
    const int wid = tid >> 6;
    const int wr = wid >> 1;
    const int wc = wid & 1;
    const int rowBase = blockIdx.y * 128;
    const int colBase = blockIdx.x * 128;

    const int r16 = lane & 15;
    const int kg = lane >> 4;
    const int srow = (lane >> 2);
    const int scol = (lane & 3) * 8;

    f32x4 acc[4][4];
#pragma unroll
    for (int m = 0; m < 4; ++m)
#pragma unroll
        for (int n = 0; n < 4; ++n) acc[m][n] = (f32x4)0.f;

#pragma unroll
    for (int h = 0; h < 2; ++h) {
#pragma unroll
        for (int c = 0; c < 2; ++c) {
            int r = wid * 32 + c * 16 + srow;
            stage16(&A[(size_t)(rowBase + r) * 96 + h * 32 + scol],
                    &lA[h][(wid * 32 + c * 16) * 32]);
            stage16(&W[(size_t)(colBase + r) * 64 + h * 32 + scol],
                    &lW[h][(wid * 32 + c * 16) * 32]);
        }
    }
    __syncthreads();

#pragma unroll
    for (int h = 0; h < 2; ++h) {
        short8 a[4], b[4];
#pragma unroll
        for (int m = 0; m < 4; ++m)
            a[m] = *(const short8*)&lA[h][(wr * 64 + m * 16 + r16) * 32 + kg * 8];
#pragma unroll
        for (int n = 0; n < 4; ++n)
            b[n] = *(const short8*)&lW[h][(wc * 64 + n * 16 + r16) * 32 + kg * 8];
#pragma unroll
        for (int m = 0; m < 4; ++m)
#pragma unroll
            for (int n = 0; n < 4; ++n)
                acc[m][n] = __builtin_amdgcn_mfma_f32_16x16x32_bf16(
                    a[m], b[n], acc[m][n], 0, 0, 0);
    }

#pragma unroll
    for (int m = 0; m < 4; ++m) {
#pragma unroll
        for (int n = 0; n < 4; ++n) {
            int gc = colBase + wc * 64 + n * 16 + r16;
            float bv = bias[gc];
#pragma unroll
            for (int j = 0; j < 4; ++j) {
                int gr = rowBase + wr * 64 + m * 16 + kg * 4 + j;
                float t = acc[m][n][j] + bv;
                t = fminf(fmaxf(t, 1e-5f), 1.0f);
                C[(size_t)gr * 2048 + gc] = __float2bfloat16(softplusf(t + bv));
            }
        }
    }
}

// ---------------------------------------------------------------------------
// G2 as bf16 MFMA split-K (reg-staged)
// ---------------------------------------------------------------------------
__global__ __launch_bounds__(256) void g2_mfma(
    const bf16* __restrict__ xcbf_f, const bf16* __restrict__ xcbf_b,
    const bf16* __restrict__ wxf, const bf16* __restrict__ wxb,
    float* __restrict__ part)   // [2][G2KS][2048][96]
{
    const int dir = blockIdx.z;
    const bf16* A = dir ? xcbf_b : xcbf_f;
    const bf16* W = dir ? wxb : wxf;
    const int rowBase = blockIdx.x * 128;
    const int kz = blockIdx.y;
    const int kBase = kz * (2048 / G2KS);

    __shared__ bf16 lA[128 * 40];
    __shared__ bf16 lW[96 * 40];

    const int tid = threadIdx.x;
    const int lane = tid & 63;
    const int wid = tid >> 6;
    const int r16 = lane & 15;
    const int kg = lane >> 4;

    f32x4 acc[2][6];
#pragma unroll
    for (int m = 0; m < 2; ++m)
#pragma unroll
        for (int n = 0; n < 6; ++n) acc[m][n] = (f32x4)0.f;

    const int srow = tid >> 2;
    const int scol = (tid & 3) * 8;

    for (int k0 = 0; k0 < 2048 / G2KS; k0 += 32) {
#pragma unroll
        for (int it = 0; it < 2; ++it) {
            int r = srow + it * 64;
            short8 va = *(const short8*)&A[(size_t)(rowBase + r) * 2048 + kBase + k0 + scol];
            *(short8*)&lA[r * 40 + scol] = va;
        }
        {
            short8 vw = *(const short8*)&W[(size_t)srow * 2048 + kBase + k0 + scol];
            *(short8*)&lW[srow * 40 + scol] = vw;
        }
        if (tid < 128) {
            int r = 64 + (tid >> 2);
            short8 vw2 = *(const short8*)&W[(size_t)r * 2048 + kBase + k0 + scol];
            *(short8*)&lW[r * 40 + scol] = vw2;
        }
        __syncthreads();

        short8 a[2], b[6];
#pragma unroll
        for (int m = 0; m < 2; ++m)
            a[m] = *(const short8*)&lA[(wid * 32 + m * 16 + r16) * 40 + kg * 8];
#pragma unroll
        for (int n = 0; n < 6; ++n)
            b[n] = *(const short8*)&lW[(n * 16 + r16) * 40 + kg * 8];
#pragma unroll
        for (int m = 0; m < 2; ++m)
#pragma unroll
            for (int n = 0; n < 6; ++n)
                acc[m][n] = __builtin_amdgcn_mfma_f32_16x16x32_bf16(
                    a[m], b[n], acc[m][n], 0, 0, 0);
        __syncthreads();
    }

    float* p = part + ((size_t)(dir * G2KS + kz) * 2048) * 96;
#pragma unroll
    for (int m = 0; m < 2; ++m) {
#pragma unroll
        for (int n = 0; n < 6; ++n) {
            int gc = n * 16 + r16;
#pragma unroll
            for (int j = 0; j < 4; ++j) {
                int gr = rowBase + wid * 32 + m * 16 + kg * 4 + j;
                p[(size_t)gr * 96 + gc] = acc[m][n][j];
            }
        }
    }
}

// g2_reduce: sum split-K partials -> fp32 xdbl AND bf16 xdbl copy (for g3)
__global__ __launch_bounds__(256) void g2_reduce(
    const float* __restrict__ part, float* __restrict__ xf, float* __restrict__ xb,
    bf16* __restrict__ xdbl_bf)
{
    int idx = blockIdx.x * 256 + threadIdx.x;
    int c = idx % 96;
    int r = (idx / 96) & 2047;
    int dir = idx / (96 * 2048);
    float s = 0.f;
#pragma unroll
    for (int ks = 0; ks < G2KS; ++ks)
        s += part[((size_t)(dir * G2KS + ks) * 2048 + r) * 96 + c];
    (dir ? xb : xf)[(size_t)r * 96 + c] = s;
    xdbl_bf[((size_t)dir * 2048 + r) * 96 + c] = __float2bfloat16(s);
}

// ---------------------------------------------------------------------------
// Fused f32 -> bf16 casts (all pre-G1 casts, one launch)
// ---------------------------------------------------------------------------
__global__ __launch_bounds__(256) void cast_all(
    const float* __restrict__ hidden, const float* __restrict__ in_proj_w,
    const float* __restrict__ xproj_w, const float* __restrict__ xproj_bw,
    const float* __restrict__ dtproj_w, const float* __restrict__ dtproj_bw,
    bf16* __restrict__ hbf, bf16* __restrict__ wbf,
    bf16* __restrict__ wxf, bf16* __restrict__ wxb,
    bf16* __restrict__ dtwf, bf16* __restrict__ dtwb)
{
    int bid = blockIdx.x;
    const float* src; bf16* dst; int base;
    if (bid < 1024)      { src = hidden;    dst = hbf;  base = bid; }
    else if (bid < 3072) { src = in_proj_w; dst = wbf;  base = bid - 1024; }
    else if (bid < 3168) { src = xproj_w;   dst = wxf;  base = bid - 3072; }
    else if (bid < 3264) { src = xproj_bw;  dst = wxb;  base = bid - 3168; }
    else if (bid < 3328) { src = dtproj_w;  dst = dtwf; base = bid - 3264; }
    else                 { src = dtproj_bw; dst = dtwb; base = bid - 3328; }
    int i = (base * 256 + threadIdx.x) * 8;
    float4 x = *(const float4*)&src[i];
    float4 y = *(const float4*)&src[i + 4];
    bf16 t[8] = { __float2bfloat16(x.x), __float2bfloat16(x.y),
                  __float2bfloat16(x.z), __float2bfloat16(x.w),
                  __float2bfloat16(y.x), __float2bfloat16(y.y),
                  __float2bfloat16(y.z), __float2bfloat16(y.w) };
    *(short8*)&dst[i] = *(short8*)t;
}

// ---------------------------------------------------------------------------
// Depthwise causal conv1d, 4 channels/thread. bf16 xz input, bf16 xc output.
// ---------------------------------------------------------------------------
__global__ __launch_bounds__(256) void conv_kernel(
    const bf16* __restrict__ xz,
    const float* __restrict__ wf, const float* __restrict__ bf,
    const float* __restrict__ wb, const float* __restrict__ bb,
    bf16* __restrict__ xcbf, bf16* __restrict__ xcbb)
{
    int idx = blockIdx.x * 256 + threadIdx.x;
    int dg = idx & 511;
    int rest = idx >> 9;
    int l = rest & (LL - 1);
    int b = (rest >> 9) & (BB - 1);
    int dir = rest >> 11;
    int d0 = dg * 4;

    const float* w = dir ? wb : wf;
    const float* bias = dir ? bb : bf;

    float4 wv[4];
#pragma unroll
    for (int c = 0; c < 4; ++c)
        wv[c] = *(const float4*)&w[(d0 + c) * DCONV];

    float4 acc = *(const float4*)&bias[d0];
#pragma unroll
    for (int k = 0; k < DCONV; ++k) {
        int j = l - (DCONV - 1) + k;
        if (j >= 0) {
            int jj = dir ? (LL - 1 - j) : j;
            short4v xv = *(const short4v*)&xz[((size_t)(b * LL + jj)) * (2 * DINNER) + d0];
            const bf16* xp = (const bf16*)&xv;
            acc.x += ((const float*)&wv[0])[k] * __bfloat162float(xp[0]);
            acc.y += ((const float*)&wv[1])[k] * __bfloat162float(xp[1]);
            acc.z += ((const float*)&wv[2])[k] * __bfloat162float(xp[2]);
            acc.w += ((const float*)&wv[3])[k] * __bfloat162float(xp[3]);
        }
    }

    size_t off = ((size_t)(b * LL + l)) * DINNER + d0;
    bf16 t[4] = { __float2bfloat16(acc.x), __float2bfloat16(acc.y),
                  __float2bfloat16(acc.z), __float2bfloat16(acc.w) };
    *(short4v*)&((dir ? xcbb : xcbf)[off]) = *(short4v*)t;
}

// ---------------------------------------------------------------------------
// Chunked scan phase 1 (bf16 delta/u inputs, arange-A fast path)
// ---------------------------------------------------------------------------
__global__ __launch_bounds__(256) void scan1_kernel(
    const float* __restrict__ Alog_f, const float* __restrict__ Alog_b,
    const float* __restrict__ xdbl_f, const float* __restrict__ xdbl_b,
    const bf16* __restrict__ xc_f, const bf16* __restrict__ xc_b,
    const bf16* __restrict__ dl_f, const bf16* __restrict__ dl_b,
    float* __restrict__ sdel, float* __restrict__ hend)
{
    const int tid = threadIdx.x;
    const int d = blockIdx.x * 256 + tid;
    const int c = blockIdx.y;
    const int z = blockIdx.z;           // dir*4 + b
    const int dir = z >> 2, b = z & 3;

    const float* Alog = dir ? Alog_b : Alog_f;
    const float* xdbl = dir ? xdbl_b : xdbl_f;
    const bf16* xc    = dir ? xc_b   : xc_f;
    const bf16* dl    = dir ? dl_b   : dl_f;
    const int rowBase = b * LL + c * SCHUNK;

    __shared__ float bs[SCHUNK][16];
#pragma unroll
    for (int i = 0; i < SCHUNK * 16 / 256; ++i) {
        int e = tid + 256 * i;
        int r = e >> 4, n = e & 15;
        bs[r][n] = xdbl[(size_t)(rowBase + r) * 96 + DTRANK + n];
    }
    __syncthreads();

    float Aa[DSTATE], h[DSTATE];
#pragma unroll
    for (int n = 0; n < DSTATE; ++n) {
        Aa[n] = -__expf(Alog[d * DSTATE + n]);
        h[n] = 0.f;
    }
    float sd = 0.f;
    const bool fast = a_is_arange(Aa);
    const float a0l2 = Aa[0] * 1.44269504f;

    float nxd = __bfloat162float(dl[(size_t)rowBase * DINNER + d]);
    float nxu = __bfloat162float(xc[(size_t)rowBase * DINNER + d]);

    if (fast) {
#pragma unroll 4
        for (int t = 0; t < SCHUNK; ++t) {
            float delta = nxd, u = nxu;
            if (t + 1 < SCHUNK) {
                size_t nrow = (size_t)(rowBase + t + 1);
                nxd = __bfloat162float(dl[nrow * DINNER + d]);
                nxu = __bfloat162float(xc[nrow * DINNER + d]);
            }
            u = fminf(fmaxf(u, -10.f), 10.f);
            float du = delta * u;
            sd += delta;
            float p[DSTATE];
            p[0] = exp2f(delta * a0l2);
#pragma unroll
            for (int n = 1; n < DSTATE; ++n)
                p[n] = p[n >> 1] * p[(n - 1) >> 1];
#pragma unroll
            for (int n = 0; n < DSTATE; ++n)
                h[n] = p[n] * h[n] + du * bs[t][n];
        }
    } else {
#pragma unroll 4
        for (int t = 0; t < SCHUNK; ++t) {
            float delta = nxd, u = nxu;
            if (t + 1 < SCHUNK) {
                size_t nrow = (size_t)(rowBase + t + 1);
                nxd = __bfloat162float(dl[nrow * DINNER + d]);
                nxu = __bfloat162float(xc[nrow * DINNER + d]);
            }
            u = fminf(fmaxf(u, -10.f), 10.f);
            float du = delta * u;
            sd += delta;
#pragma unroll
            for (int n = 0; n < DSTATE; ++n)
                h[n] = __expf(delta * Aa[n]) * h[n] + du * bs[t][n];
        }
    }

    size_t base = (size_t)z * SNC + c;
    sdel[base * DINNER + d] = sd;
#pragma unroll
    for (int n = 0; n < DSTATE; ++n)
        hend[(base * DSTATE + n) * DINNER + d] = h[n];
}

// ---------------------------------------------------------------------------
// Combine (n-parallel, IN PLACE)
// ---------------------------------------------------------------------------
__global__ __launch_bounds__(256) void scan_combine(
    const float* __restrict__ Alog_f, const float* __restrict__ Alog_b,
    const float* __restrict__ sdel, float* __restrict__ hend)
{
    int g = blockIdx.x * 256 + threadIdx.x;
    int d = g & (DINNER - 1);
    int n = (g >> 11) & (DSTATE - 1);
    int z = g >> 15;
    const float* Alog = (z >> 2) ? Alog_b : Alog_f;

    float Aa = -__expf(Alog[d * DSTATE + n]);
    float hr = 0.f;
    for (int c = 0; c < SNC; ++c) {
        size_t base = (size_t)z * SNC + c;
        size_t idx = (base * DSTATE + n) * DINNER + d;
        float he = hend[idx];
        hend[idx] = hr;
        float sd = sdel[base * DINNER + d];
        hr = __expf(sd * Aa) * hr + he;
    }
}

// ---------------------------------------------------------------------------
// Chunked scan phase 2 (bf16 in, bf16 y out in place, arange-A fast path)
// ---------------------------------------------------------------------------
__global__ __launch_bounds__(256) void scan2_kernel(
    const float* __restrict__ Alog_f, const float* __restrict__ Alog_b,
    const float* __restrict__ Df, const float* __restrict__ Db,
    const float* __restrict__ xdbl_f, const float* __restrict__ xdbl_b,
    const bf16* __restrict__ xc_f, const bf16* __restrict__ xc_b,
    const float* __restrict__ hin,
    bf16* __restrict__ dl_f, bf16* __restrict__ dl_b)
{
    const int tid = threadIdx.x;
    const int d = blockIdx.x * 256 + tid;
    const int c = blockIdx.y;
    const int z = blockIdx.z;
    const int dir = z >> 2, b = z & 3;

    const float* Alog = dir ? Alog_b : Alog_f;
    const float* xdbl = dir ? xdbl_b : xdbl_f;
    const bf16* xc    = dir ? xc_b   : xc_f;
    bf16* dl          = dir ? dl_b   : dl_f;
    const int rowBase = b * LL + c * SCHUNK;

    __shared__ float bs[SCHUNK][32];
#pragma unroll
    for (int i = 0; i < SCHUNK * 32 / 256; ++i) {
        int e = tid + 256 * i;
        int r = e >> 5, n = e & 31;
        bs[r][n] = xdbl[(size_t)(rowBase + r) * 96 + DTRANK + n];
    }
    __syncthreads();

    float Dv = (dir ? Db : Df)[d];
    size_t base = (size_t)z * SNC + c;
    float Aa[DSTATE], h[DSTATE];
#pragma unroll
    for (int n = 0; n < DSTATE; ++n) {
        Aa[n] = -__expf(Alog[d * DSTATE + n]);
        h[n] = hin[(base * DSTATE + n) * DINNER + d];
    }
    const bool fast = a_is_arange(Aa);
    const float a0l2 = Aa[0] * 1.44269504f;

    float nxd = __bfloat162float(dl[(size_t)rowBase * DINNER + d]);
    float nxu = __bfloat162float(xc[(size_t)rowBase * DINNER + d]);

    if (fast) {
#pragma unroll 4
        for (int t = 0; t < SCHUNK; ++t) {
            float delta = nxd, u = nxu;
            if (t + 1 < SCHUNK) {
                size_t nrow = (size_t)(rowBase + t + 1);
                nxd = __bfloat162float(dl[nrow * DINNER + d]);
                nxu = __bfloat162float(xc[nrow * DINNER + d]);
            }
            u = fminf(fmaxf(u, -10.f), 10.f);
            float du = delta * u;
            float p[DSTATE];
            p[0] = exp2f(delta * a0l2);
#pragma unroll
            for (int n = 1; n < DSTATE; ++n)
                p[n] = p[n >> 1] * p[(n - 1) >> 1];
            float y = 0.f;
#pragma unroll
            for (int n = 0; n < DSTATE; ++n) {
                h[n] = p[n] * h[n] + du * bs[t][n];
                y += h[n] * bs[t][DSTATE + n];
            }
            dl[(size_t)(rowBase + t) * DINNER + d] = __float2bfloat16(y + u * Dv);
        }
    } else {
#pragma unroll 4
        for (int t = 0; t < SCHUNK; ++t) {
            float delta = nxd, u = nxu;
            if (t + 1 < SCHUNK) {
                size_t nrow = (size_t)(rowBase + t + 1);
                nxd = __bfloat162float(dl[nrow * DINNER + d]);
                nxu = __bfloat162float(xc[nrow * DINNER + d]);
            }
            u = fminf(fmaxf(u, -10.f), 10.f);
            float du = delta * u;
            float y = 0.f;
#pragma unroll
            for (int n = 0; n < DSTATE; ++n) {
                h[n] = __expf(delta * Aa[n]) * h[n] + du * bs[t][n];
                y += h[n] * bs[t][DSTATE + n];
            }
            dl[(size_t)(rowBase + t) * DINNER + d] = __float2bfloat16(y + u * Dv);
        }
    }
}

// ---------------------------------------------------------------------------
// Gate + out_pw cast fused (bf16 y and z inputs)
// ---------------------------------------------------------------------------
__global__ __launch_bounds__(256) void gate_cast(
    const bf16* __restrict__ yf, const bf16* __restrict__ yb,
    const bf16* __restrict__ xz, bf16* __restrict__ ytot,
    const float* __restrict__ out_pw, bf16* __restrict__ obf)
{
    int bid = blockIdx.x;
    if (bid < 16384) {
        int idx = bid * 256 + threadIdx.x;
        int d = idx & (DINNER - 1);
        int l = (idx >> 11) & (LL - 1);
        int b = idx >> 20;
        size_t rowf = (size_t)(b * LL + l);
        size_t rowb = (size_t)(b * LL + (LL - 1 - l));
        float y = __bfloat162float(yf[rowf * DINNER + d]) +
                  __bfloat162float(yb[rowb * DINNER + d]);
        float z = __bfloat162float(xz[rowf * (2 * DINNER) + DINNER + d]);
        float s = z / (1.f + __expf(-z));
        ytot[rowf * DINNER + d] = __float2bfloat16(y * s);
    } else {
        int i = ((bid - 16384) * 256 + threadIdx.x) * 8;
        float4 x = *(const float4*)&out_pw[i];
        float4 y = *(const float4*)&out_pw[i + 4];
        bf16 t[8] = { __float2bfloat16(x.x), __float2bfloat16(x.y),
                      __float2bfloat16(x.z), __float2bfloat16(x.w),
                      __float2bfloat16(y.x), __float2bfloat16(y.y),
                      __float2bfloat16(y.z), __float2bfloat16(y.w) };
        *(short8*)&obf[i] = *(short8*)t;
    }
}

// ---------------------------------------------------------------------------
extern "C" void kernel_launch(void* const* d_in, const int* in_sizes, int n_in,
                              void* d_out, int out_size, void* d_ws, size_t ws_size,
                              hipStream_t stream)
{
    const float* hidden    = (const float*)d_in[0];
    const float* in_proj_w = (const float*)d_in[1];
    const float* conv_w    = (const float*)d_in[2];
    const float* conv_b    = (const float*)d_in[3];
    const float* xproj_w   = (const float*)d_in[4];
    const float* dtproj_w  = (const float*)d_in[5];
    const float* dtproj_b  = (const float*)d_in[6];
    const float* A_log     = (const float*)d_in[7];
    const float* Dvec      = (const float*)d_in[8];
    const float* conv_bw   = (const float*)d_in[9];
    const float* conv_bb   = (const float*)d_in[10];
    const float* xproj_bw  = (const float*)d_in[11];
    const float* dtproj_bw = (const float*)d_in[12];
    const float* dtproj_bb = (const float*)d_in[13];
    const float* A_b_log   = (const float*)d_in[14];
    const float* D_b       = (const float*)d_in[15];
    const float* out_pw    = (const float*)d_in[16];
    float* out = (float*)d_out;

    // Workspace layout (f32 elements). Total 31,916,032 = 127.7 MB.
    float* ws = (float*)d_ws;
    float* xzR     = ws;                       // 8388608 region: bf16 xz (uses first half)
    float* xcR_f   = xzR + 8388608;            // 4194304 region: bf16 xc fwd
    float* xcR_b   = xcR_f + 4194304;          // 4194304 region: bf16 xc bwd
    float* xdbl_f  = xcR_b + 4194304;          // 196608
    float* xdbl_b  = xdbl_f + 196608;          // 196608
    float* dlR_f   = xdbl_b + 196608;          // 4194304 region: bf16 delta/y fwd
    float* dlR_b   = dlR_f + 4194304;          // 4194304 region: bf16 delta/y bwd
    float* g2part  = dlR_b + 4194304;          // 1572864
    float* sdel    = g2part + 1572864;         // 262144
    float* hend    = sdel + 262144;            // 4194304; becomes hin in place
    float* smallb  = hend + 4194304;           // 327680

    // bf16 views / aliases (liveness audited R13/R14):
    bf16* xzbf = (bf16*)xzR;                   // G1 -> conv (x half) + gate (z half)
    bf16* xcbf = (bf16*)xcR_f;                 // conv -> g2/scan1/scan2; then dead
    bf16* xcbb = (bf16*)xcR_b;
    bf16* dlbf_f = (bf16*)dlR_f;               // g3 -> scan1/scan2(y) -> gate
    bf16* dlbf_b = (bf16*)dlR_b;
    bf16* hbf = (bf16*)dlR_f;                  // cast_all->G1; overwritten by g3 later
    bf16* wbf = (bf16*)(dlR_f + 1048576);      // cast_all->G1
    bf16* wxf = (bf16*)dlR_b;                  // cast_all->g2; overwritten by g3 later
    bf16* wxb = (bf16*)(dlR_b + 98304);
    bf16* xdbl_bf = (bf16*)smallb;             // g2_reduce->g3
    bf16* dtw_bf  = (bf16*)(smallb + 196608);  // cast_all->g3
    bf16* ytot_bf = (bf16*)xcR_f;              // gate->g4 (xc dead after scan2)
    bf16* obf = (bf16*)xcR_b;                  // gate_cast->g4
    float* g4part = dlR_f;                     // g4 partials (dl dead after gate)

    dim3 blk(256);

    // all pre-G1 casts in one launch
    cast_all<<<dim3(3392), blk, 0, stream>>>(
        hidden, in_proj_w, xproj_w, xproj_bw, dtproj_w, dtproj_bw,
        hbf, wbf, wxf, wxb, dtw_bf, dtw_bf + 131072);

    // G1: xz = hidden @ in_proj_w.T  (bf16 output, twin-buffer BK=64)
    gemm_bf16<<<dim3(4096 / 128, MROWS / 128), blk, 0, stream>>>(
        hbf, wbf, xzbf, 4096, 1024, 1024, 1024, 4096);

    // conv both dirs (bf16 in/out), 4 channels/thread
    conv_kernel<<<dim3(2 * BB * LL * DINNER / 4 / 256), blk, 0, stream>>>(
        xzbf, conv_w, conv_b, conv_bw, conv_bb, xcbf, xcbb);

    // G2 via bf16 MFMA split-K
    g2_mfma<<<dim3(16, G2KS, 2), blk, 0, stream>>>(
        xcbf, xcbb, wxf, wxb, g2part);
    g2_reduce<<<dim3(2 * 2048 * 96 / 256), blk, 0, stream>>>(
        g2part, xdbl_f, xdbl_b, xdbl_bf);

    // G3 via bf16 MFMA (both dirs) -> bf16 delta
    g3_mfma<<<dim3(16, 16, 2), blk, 0, stream>>>(
        xdbl_bf, dtw_bf, dtproj_b, dtproj_bb, dlbf_f, dlbf_b);

    // chunked scan (bf16 delta/u, SCHUNK=32, in-place combine, arange-A fast)
    scan1_kernel<<<dim3(DINNER / 256, SNC, 8), blk, 0, stream>>>(
        A_log, A_b_log, xdbl_f, xdbl_b, xcbf, xcbb, dlbf_f, dlbf_b, sdel, hend);
    scan_combine<<<dim3(2 * BB * DSTATE * DINNER / 256), blk, 0, stream>>>(
        A_log, A_b_log, sdel, hend);
    scan2_kernel<<<dim3(DINNER / 256, SNC, 8), blk, 0, stream>>>(
        A_log, A_b_log, Dvec, D_b, xdbl_f, xdbl_b, xcbf, xcbb, hend, dlbf_f, dlbf_b);

    // gate -> bf16 ytot (overwrites xc region), + out_pw cast (fused)
    gate_cast<<<dim3(16384 + 1024), blk, 0, stream>>>(
        dlbf_f, dlbf_b, xzbf, ytot_bf, out_pw, obf);

    // G4 split-K=2 (twin-buffer BK=64) + fused reduce/nan_to_num
    g4_mfma<<<dim3(1024 / 128, MROWS / 128, 2), blk, 0, stream>>>(
        ytot_bf, obf, g4part);
    g4_reduce<<<dim3(2048 * 1024 / 4 / 256), blk, 0, stream>>>(g4part, out);
}